// Round 2
// baseline (644.515 us; speedup 1.0000x reference)
//
#include <hip/hip_runtime.h>

#define N_NODES 100000
#define N_EDGES 1600000
#define DIM     128
#define EPS_BN  1e-5f
#define NB      512      // coarse buckets
#define NPB     196      // nodes per bucket (512*196 = 100352 >= 100000)
#define EPB     3125     // edges per block in binning (512*3125 == N_EDGES)
#define CAP     4096     // LDS col staging capacity in build_csr (mean 3136, sigma~56)

// ---------------------------------------------------------------------------
// edge_index dtype detector: if data is int64 (little-endian, values < 2^31),
// every odd int32 word (high half) is 0. flag=1 => int64.
// ---------------------------------------------------------------------------
__global__ void detect_dtype(const int* raw, int* flag) {
    long long s = 0;
    for (int k = 0; k < 64; ++k) s += raw[2 * k + 1];
    *flag = (s == 0) ? 1 : 0;
}

__device__ __forceinline__ int load_row(const void* eidx, int is64, int e) {
    if (is64) return (int)((const long long*)eidx)[e];
    return ((const int*)eidx)[e];
}
__device__ __forceinline__ int load_col(const void* eidx, int is64, int e) {
    if (is64) return (int)((const long long*)eidx)[N_EDGES + e];
    return ((const int*)eidx)[N_EDGES + e];
}

// ---------------------------------------------------------------------------
// Pass A0: coarse bucket histogram (LDS-privatized, 1 global atomic / bucket
// / block -> 262K atomics instead of 1.6M).
// ---------------------------------------------------------------------------
__global__ __launch_bounds__(256) void bucket_hist(const void* eidx,
                                                   const int* flag,
                                                   int* bcnt) {
    __shared__ int lh[NB];
    for (int i = threadIdx.x; i < NB; i += 256) lh[i] = 0;
    __syncthreads();
    int is64 = *flag;
    int base = blockIdx.x * EPB;
    for (int i = threadIdx.x; i < EPB; i += 256) {
        int r = load_row(eidx, is64, base + i);
        atomicAdd(&lh[r / NPB], 1);
    }
    __syncthreads();
    for (int i = threadIdx.x; i < NB; i += 256)
        if (lh[i]) atomicAdd(&bcnt[i], lh[i]);
}

// exclusive scan of 512 bucket counts; also seeds the claim cursors and the
// CSR sentinel row_start[N] = E.
__global__ void scan512(const int* bcnt, int* bstart, int* bcur, int* rowst) {
    __shared__ int tmp[NB];
    int t = threadIdx.x;
    int v = bcnt[t];
    tmp[t] = v;
    __syncthreads();
    for (int off = 1; off < NB; off <<= 1) {
        int a = (t >= off) ? tmp[t - off] : 0;
        __syncthreads();
        tmp[t] += a;
        __syncthreads();
    }
    bstart[t] = tmp[t] - v;
    bcur[t]   = tmp[t] - v;
    if (t == NB - 1) { bstart[NB] = N_EDGES; rowst[N_NODES] = N_EDGES; }
}

// ---------------------------------------------------------------------------
// Pass A1: scatter (row,col) pairs into bucket-contiguous regions. Each block
// claims a contiguous range per bucket with ONE global atomic, so writes land
// in runs of ~6 consecutive 8B pairs (48B) instead of isolated 4B stores.
// ---------------------------------------------------------------------------
__global__ __launch_bounds__(256) void bin_scatter(const void* eidx,
                                                   const int* flag, int* bcur,
                                                   uint2* pairs) {
    __shared__ int lh[NB];
    __shared__ int lbase[NB];
    for (int i = threadIdx.x; i < NB; i += 256) lh[i] = 0;
    __syncthreads();
    int is64 = *flag;
    int base = blockIdx.x * EPB;
    for (int i = threadIdx.x; i < EPB; i += 256) {
        int r = load_row(eidx, is64, base + i);
        atomicAdd(&lh[r / NPB], 1);
    }
    __syncthreads();
    for (int i = threadIdx.x; i < NB; i += 256) {
        int c = lh[i];
        lbase[i] = c ? atomicAdd(&bcur[i], c) : 0;
        lh[i] = 0;
    }
    __syncthreads();
    for (int i = threadIdx.x; i < EPB; i += 256) {
        int r = load_row(eidx, is64, base + i);
        int c = load_col(eidx, is64, base + i);
        int b = r / NPB;
        int pos = lbase[b] + atomicAdd(&lh[b], 1);
        pairs[pos] = make_uint2((unsigned)r, (unsigned)c);
    }
}

// ---------------------------------------------------------------------------
// Pass B: one block per bucket. All fine-grained scatter happens in LDS;
// global writes of cols / row_start are fully coalesced.
// ---------------------------------------------------------------------------
__global__ __launch_bounds__(256) void build_csr(const uint2* __restrict__ pairs,
                                                 const int* __restrict__ bstart,
                                                 int* __restrict__ rowst,
                                                 int* __restrict__ cols) {
    __shared__ int hist[256];      // NPB=196 padded to 256
    __shared__ int excl[256];
    __shared__ int cur[256];
    __shared__ int colbuf[CAP];
    int b = blockIdx.x;
    int node0 = b * NPB;
    int nn = N_NODES - node0;
    if (nn <= 0) return;
    if (nn > NPB) nn = NPB;
    int s = bstart[b], e = bstart[b + 1];
    int cnt = e - s;
    int t = threadIdx.x;
    hist[t] = 0;
    __syncthreads();
    for (int i = t; i < cnt; i += 256)
        atomicAdd(&hist[(int)pairs[s + i].x - node0], 1);
    __syncthreads();
    int v = hist[t];
    excl[t] = v;
    __syncthreads();
    for (int off = 1; off < 256; off <<= 1) {
        int a = (t >= off) ? excl[t - off] : 0;
        __syncthreads();
        excl[t] += a;
        __syncthreads();
    }
    int ex = excl[t] - v;          // exclusive scan result
    if (t < nn) rowst[node0 + t] = s + ex;
    cur[t] = ex;
    __syncthreads();
    if (cnt <= CAP) {
        for (int i = t; i < cnt; i += 256) {
            uint2 pr = pairs[s + i];
            int pos = atomicAdd(&cur[(int)pr.x - node0], 1);
            colbuf[pos] = (int)pr.y;
        }
        __syncthreads();
        for (int i = t; i < cnt; i += 256) cols[s + i] = colbuf[i];
    } else {                        // overflow fallback (never for this input)
        for (int i = t; i < cnt; i += 256) {
            uint2 pr = pairs[s + i];
            int pos = atomicAdd(&cur[(int)pr.x - node0], 1);
            cols[s + pos] = (int)pr.y;
        }
    }
}

// ---------------------------------------------------------------------------
// Aggregation + residual: H[n] = x[n] + sum_{c in nbrs(n)} x[c]
// One wave per node; lane holds float2 (64 lanes * 8B = full 512B row).
// ---------------------------------------------------------------------------
__global__ void agg_kernel(const float* __restrict__ x,
                           const int* __restrict__ row_start,
                           const int* __restrict__ cols,
                           float* __restrict__ H) {
    int wave = threadIdx.x >> 6;
    int lane = threadIdx.x & 63;
    int node = blockIdx.x * 4 + wave;
    if (node >= N_NODES) return;
    float2 acc = ((const float2*)(x + (size_t)node * DIM))[lane];
    int s = row_start[node], e = row_start[node + 1];
    int deg = e - s;
    int c_l = (s + lane < e) ? cols[s + lane] : 0;
    int dmain = deg < 64 ? deg : 64;
    for (int j = 0; j < dmain; ++j) {
        int c = __shfl(c_l, j);
        float2 v = ((const float2*)(x + (size_t)c * DIM))[lane];
        acc.x += v.x; acc.y += v.y;
    }
    for (int j = s + 64; j < e; ++j) {
        int c = cols[j];
        float2 v = ((const float2*)(x + (size_t)c * DIM))[lane];
        acc.x += v.x; acc.y += v.y;
    }
    ((float2*)(H + (size_t)node * DIM))[lane] = acc;
}

// ---------------------------------------------------------------------------
// Vector-f32 GEMM, in-place on H: H = act(H @ W + b). 80-row tiles, W staged
// through LDS in 4 k-chunks of 32. k unrolled by 4 with float4 H reads:
// per 4k per wave: 14 ds_read_b128 (~168 LDS-pipe cyc) vs 160 v_fma (320 VALU
// cyc) -> VALU-bound. STATS fuses BN column sum/sumsq.
// ---------------------------------------------------------------------------
template <bool RELU, bool STATS>
__global__ __launch_bounds__(256) void gemm_kernel(float* __restrict__ H,
                                                   const float* __restrict__ W,
                                                   const float* __restrict__ b,
                                                   float* __restrict__ stats) {
    __shared__ float Hs[80 * DIM];
    __shared__ float Ws[32 * DIM];
    __shared__ float csum[DIM], csq[DIM];
    int t = threadIdx.x;
    int row0 = blockIdx.x * 80;

    const float4* Hg = (const float4*)(H + (size_t)row0 * DIM);
    float4* Hs4 = (float4*)Hs;
#pragma unroll
    for (int i = 0; i < 10; ++i) Hs4[t + 256 * i] = Hg[t + 256 * i];
    if (STATS && t < DIM) { csum[t] = 0.f; csq[t] = 0.f; }

    int tj = t & 31, tr = t >> 5;
    float4 acc[10];
    float4 bb = ((const float4*)b)[tj];
#pragma unroll
    for (int m = 0; m < 10; ++m) acc[m] = bb;

    float4* Ws4 = (float4*)Ws;
    for (int kb = 0; kb < 4; ++kb) {
        __syncthreads();
        const float4* Wg = (const float4*)(W + kb * 32 * DIM);
#pragma unroll
        for (int i = 0; i < 4; ++i) Ws4[t + 256 * i] = Wg[t + 256 * i];
        __syncthreads();
#pragma unroll
        for (int k4 = 0; k4 < 8; ++k4) {
            float4 w0 = Ws4[(k4 * 4 + 0) * 32 + tj];
            float4 w1 = Ws4[(k4 * 4 + 1) * 32 + tj];
            float4 w2 = Ws4[(k4 * 4 + 2) * 32 + tj];
            float4 w3 = Ws4[(k4 * 4 + 3) * 32 + tj];
#pragma unroll
            for (int m = 0; m < 10; ++m) {
                float4 h = Hs4[(tr + 8 * m) * 32 + kb * 8 + k4];
                acc[m].x += h.x * w0.x + h.y * w1.x + h.z * w2.x + h.w * w3.x;
                acc[m].y += h.x * w0.y + h.y * w1.y + h.z * w2.y + h.w * w3.y;
                acc[m].z += h.x * w0.z + h.y * w1.z + h.z * w2.z + h.w * w3.z;
                acc[m].w += h.x * w0.w + h.y * w1.w + h.z * w2.w + h.w * w3.w;
            }
        }
    }

    float4* Ho = (float4*)(H + (size_t)row0 * DIM);
    float4 s4 = {0.f, 0.f, 0.f, 0.f}, q4 = {0.f, 0.f, 0.f, 0.f};
#pragma unroll
    for (int m = 0; m < 10; ++m) {
        float4 v = acc[m];
        if (RELU) {
            v.x = fmaxf(v.x, 0.f); v.y = fmaxf(v.y, 0.f);
            v.z = fmaxf(v.z, 0.f); v.w = fmaxf(v.w, 0.f);
        }
        Ho[(tr + 8 * m) * 32 + tj] = v;
        if (STATS) {
            s4.x += v.x; s4.y += v.y; s4.z += v.z; s4.w += v.w;
            q4.x += v.x * v.x; q4.y += v.y * v.y;
            q4.z += v.z * v.z; q4.w += v.w * v.w;
        }
    }
    if (STATS) {
        atomicAdd(&csum[4 * tj + 0], s4.x); atomicAdd(&csum[4 * tj + 1], s4.y);
        atomicAdd(&csum[4 * tj + 2], s4.z); atomicAdd(&csum[4 * tj + 3], s4.w);
        atomicAdd(&csq[4 * tj + 0], q4.x);  atomicAdd(&csq[4 * tj + 1], q4.y);
        atomicAdd(&csq[4 * tj + 2], q4.z);  atomicAdd(&csq[4 * tj + 3], q4.w);
        __syncthreads();
        if (t < DIM) {
            atomicAdd(&stats[t], csum[t]);
            atomicAdd(&stats[DIM + t], csq[t]);
        }
    }
}

__global__ void finalize_stats(float* stats, const float* gamma,
                               const float* beta) {
    int t = threadIdx.x;                         // 128 threads
    float mean = stats[t] * (1.0f / N_NODES);
    float m2 = stats[DIM + t] * (1.0f / N_NODES);
    float var = m2 - mean * mean;
    float inv = rsqrtf(var + EPS_BN);
    float sc = gamma[t] * inv;
    float sh = beta[t] - mean * sc;
    stats[t] = sc;
    stats[DIM + t] = sh;
}

__global__ void bn_apply(const float* __restrict__ H,
                         const float* __restrict__ stats,
                         float* __restrict__ out) {
    int i = blockIdx.x * 256 + threadIdx.x;
    int j4 = i & 31;
    float4 h = ((const float4*)H)[i];
    float4 sc = ((const float4*)stats)[j4];
    float4 sh = ((const float4*)(stats + DIM))[j4];
    float4 o;
    o.x = h.x * sc.x + sh.x; o.y = h.y * sc.y + sh.y;
    o.z = h.z * sc.z + sh.z; o.w = h.w * sc.w + sh.w;
    ((float4*)out)[i] = o;
}

// ---------------------------------------------------------------------------
extern "C" void kernel_launch(void* const* d_in, const int* in_sizes, int n_in,
                              void* d_out, int out_size, void* d_ws,
                              size_t ws_size, hipStream_t stream) {
    (void)in_sizes; (void)n_in; (void)out_size; (void)ws_size;
    const float* x     = (const float*)d_in[0];
    const void*  eidx  = d_in[1];
    const float* W1    = (const float*)d_in[2];
    const float* b1    = (const float*)d_in[3];
    const float* W2    = (const float*)d_in[4];
    const float* b2    = (const float*)d_in[5];
    const float* gamma = (const float*)d_in[6];
    const float* beta  = (const float*)d_in[7];
    float* out = (float*)d_out;

    char* p = (char*)d_ws;
    auto alloc = [&](size_t bytes) {
        char* r = p;
        p += (bytes + 255) & ~(size_t)255;
        return r;
    };
    float* H      = (float*)alloc((size_t)N_NODES * DIM * 4);   // 51.2 MB
    uint2* pairs  = (uint2*)alloc((size_t)N_EDGES * 8);         // 12.8 MB
    int*   cols   = (int*)alloc((size_t)N_EDGES * 4);           // 6.4 MB
    int*   rowst  = (int*)alloc((size_t)(N_NODES + 1) * 4);
    int*   bcnt   = (int*)alloc(NB * 4);
    int*   bstart = (int*)alloc((NB + 1) * 4);
    int*   bcur   = (int*)alloc(NB * 4);
    float* stats  = (float*)alloc(2 * DIM * 4);
    int*   flag   = (int*)alloc(16);

    hipMemsetAsync(bcnt, 0, NB * 4, stream);
    hipMemsetAsync(stats, 0, 2 * DIM * 4, stream);

    detect_dtype<<<1, 1, 0, stream>>>((const int*)eidx, flag);
    bucket_hist<<<NB, 256, 0, stream>>>(eidx, flag, bcnt);
    scan512<<<1, NB, 0, stream>>>(bcnt, bstart, bcur, rowst);
    bin_scatter<<<NB, 256, 0, stream>>>(eidx, flag, bcur, pairs);
    build_csr<<<NB, 256, 0, stream>>>(pairs, bstart, rowst, cols);

    agg_kernel<<<N_NODES / 4, 256, 0, stream>>>(x, rowst, cols, H);

    gemm_kernel<true, false><<<N_NODES / 80, 256, 0, stream>>>(H, W1, b1,
                                                               nullptr);
    gemm_kernel<false, true><<<N_NODES / 80, 256, 0, stream>>>(H, W2, b2,
                                                               stats);
    finalize_stats<<<1, 128, 0, stream>>>(stats, gamma, beta);
    bn_apply<<<(N_NODES * DIM / 4) / 256, 256, 0, stream>>>(H, stats, out);
}

// Round 3
// 396.519 us; speedup vs baseline: 1.6254x; 1.6254x over previous
//
#include <hip/hip_runtime.h>

#define N_NODES 100000
#define N_EDGES 1600000
#define DIM     128
#define EPS_BN  1e-5f
#define NB      512      // coarse buckets
#define NPB     196      // nodes per bucket (512*196 >= 100000)
#define EPB     3125     // edges per block in binning (512*3125 == N_EDGES)
#define CAP     4096     // LDS col staging capacity in build_csr
#define M_TILE  64
#define M_PAD   100032   // 1563 * 64
#define LPITCH  136      // LDS pitch in bf16 units: 272B = 17*16B (b128-aligned, 2-way banks)

typedef __attribute__((ext_vector_type(8))) short short8;
typedef __attribute__((ext_vector_type(4))) float floatx4;

__device__ __forceinline__ unsigned short f2bf(float f) {   // RNE bf16 bits
    unsigned u = __float_as_uint(f);
    return (unsigned short)((u + 0x7FFF + ((u >> 16) & 1)) >> 16);
}
__device__ __forceinline__ float bf2f(unsigned short b) {
    return __uint_as_float((unsigned)b << 16);
}

// ---------------------------------------------------------------------------
// edge_index dtype detector (int64 layout => odd int32 words all zero)
// ---------------------------------------------------------------------------
__global__ void detect_dtype(const int* raw, int* flag) {
    long long s = 0;
    for (int k = 0; k < 64; ++k) s += raw[2 * k + 1];
    *flag = (s == 0) ? 1 : 0;
}

__device__ __forceinline__ int load_row(const void* eidx, int is64, int e) {
    if (is64) return (int)((const long long*)eidx)[e];
    return ((const int*)eidx)[e];
}
__device__ __forceinline__ int load_col(const void* eidx, int is64, int e) {
    if (is64) return (int)((const long long*)eidx)[N_EDGES + e];
    return ((const int*)eidx)[N_EDGES + e];
}

// ---------------------------------------------------------------------------
// CSR build via 2-level counting sort (all fine scatter in LDS)
// ---------------------------------------------------------------------------
__global__ __launch_bounds__(256) void bucket_hist(const void* eidx,
                                                   const int* flag,
                                                   int* bcnt) {
    __shared__ int lh[NB];
    for (int i = threadIdx.x; i < NB; i += 256) lh[i] = 0;
    __syncthreads();
    int is64 = *flag;
    int base = blockIdx.x * EPB;
    for (int i = threadIdx.x; i < EPB; i += 256) {
        int r = load_row(eidx, is64, base + i);
        atomicAdd(&lh[r / NPB], 1);
    }
    __syncthreads();
    for (int i = threadIdx.x; i < NB; i += 256)
        if (lh[i]) atomicAdd(&bcnt[i], lh[i]);
}

__global__ void scan512(const int* bcnt, int* bstart, int* bcur, int* rowst) {
    __shared__ int tmp[NB];
    int t = threadIdx.x;
    int v = bcnt[t];
    tmp[t] = v;
    __syncthreads();
    for (int off = 1; off < NB; off <<= 1) {
        int a = (t >= off) ? tmp[t - off] : 0;
        __syncthreads();
        tmp[t] += a;
        __syncthreads();
    }
    bstart[t] = tmp[t] - v;
    bcur[t]   = tmp[t] - v;
    if (t == NB - 1) { bstart[NB] = N_EDGES; rowst[N_NODES] = N_EDGES; }
}

__global__ __launch_bounds__(256) void bin_scatter(const void* eidx,
                                                   const int* flag, int* bcur,
                                                   uint2* pairs) {
    __shared__ int lh[NB];
    __shared__ int lbase[NB];
    for (int i = threadIdx.x; i < NB; i += 256) lh[i] = 0;
    __syncthreads();
    int is64 = *flag;
    int base = blockIdx.x * EPB;
    for (int i = threadIdx.x; i < EPB; i += 256) {
        int r = load_row(eidx, is64, base + i);
        atomicAdd(&lh[r / NPB], 1);
    }
    __syncthreads();
    for (int i = threadIdx.x; i < NB; i += 256) {
        int c = lh[i];
        lbase[i] = c ? atomicAdd(&bcur[i], c) : 0;
        lh[i] = 0;
    }
    __syncthreads();
    for (int i = threadIdx.x; i < EPB; i += 256) {
        int r = load_row(eidx, is64, base + i);
        int c = load_col(eidx, is64, base + i);
        int b = r / NPB;
        int pos = lbase[b] + atomicAdd(&lh[b], 1);
        pairs[pos] = make_uint2((unsigned)r, (unsigned)c);
    }
}

__global__ __launch_bounds__(256) void build_csr(const uint2* __restrict__ pairs,
                                                 const int* __restrict__ bstart,
                                                 int* __restrict__ rowst,
                                                 int* __restrict__ cols) {
    __shared__ int hist[256];
    __shared__ int excl[256];
    __shared__ int cur[256];
    __shared__ int colbuf[CAP];
    int b = blockIdx.x;
    int node0 = b * NPB;
    int nn = N_NODES - node0;
    if (nn <= 0) return;
    if (nn > NPB) nn = NPB;
    int s = bstart[b], e = bstart[b + 1];
    int cnt = e - s;
    int t = threadIdx.x;
    hist[t] = 0;
    __syncthreads();
    for (int i = t; i < cnt; i += 256)
        atomicAdd(&hist[(int)pairs[s + i].x - node0], 1);
    __syncthreads();
    int v = hist[t];
    excl[t] = v;
    __syncthreads();
    for (int off = 1; off < 256; off <<= 1) {
        int a = (t >= off) ? excl[t - off] : 0;
        __syncthreads();
        excl[t] += a;
        __syncthreads();
    }
    int ex = excl[t] - v;
    if (t < nn) rowst[node0 + t] = s + ex;
    cur[t] = ex;
    __syncthreads();
    if (cnt <= CAP) {
        for (int i = t; i < cnt; i += 256) {
            uint2 pr = pairs[s + i];
            int pos = atomicAdd(&cur[(int)pr.x - node0], 1);
            colbuf[pos] = (int)pr.y;
        }
        __syncthreads();
        for (int i = t; i < cnt; i += 256) cols[s + i] = colbuf[i];
    } else {
        for (int i = t; i < cnt; i += 256) {
            uint2 pr = pairs[s + i];
            int pos = atomicAdd(&cur[(int)pr.x - node0], 1);
            cols[s + pos] = (int)pr.y;
        }
    }
}

// ---------------------------------------------------------------------------
// Aggregation + residual, output bf16: Hbf[n] = bf16(x[n] + sum x[c])
// One wave per node; lane holds float2; packed 4B bf16x2 store.
// ---------------------------------------------------------------------------
__global__ void agg_kernel(const float* __restrict__ x,
                           const int* __restrict__ row_start,
                           const int* __restrict__ cols,
                           unsigned short* __restrict__ Hbf) {
    int wave = threadIdx.x >> 6;
    int lane = threadIdx.x & 63;
    int node = blockIdx.x * 4 + wave;
    if (node >= N_NODES) return;
    float2 acc = ((const float2*)(x + (size_t)node * DIM))[lane];
    int s = row_start[node], e = row_start[node + 1];
    int deg = e - s;
    int c_l = (s + lane < e) ? cols[s + lane] : 0;
    int dmain = deg < 64 ? deg : 64;
    for (int j = 0; j < dmain; ++j) {
        int c = __shfl(c_l, j);
        float2 v = ((const float2*)(x + (size_t)c * DIM))[lane];
        acc.x += v.x; acc.y += v.y;
    }
    for (int j = s + 64; j < e; ++j) {
        int c = cols[j];
        float2 v = ((const float2*)(x + (size_t)c * DIM))[lane];
        acc.x += v.x; acc.y += v.y;
    }
    unsigned pack = (unsigned)f2bf(acc.x) | ((unsigned)f2bf(acc.y) << 16);
    ((unsigned*)Hbf)[(size_t)node * 64 + lane] = pack;
}

// ---------------------------------------------------------------------------
// W (128x128 f32, [k][n]) -> bf16 transposed [n][k]. Tiny; L2-resident.
// ---------------------------------------------------------------------------
__global__ void convert_w(const float* __restrict__ W1,
                          const float* __restrict__ W2,
                          unsigned short* __restrict__ W1t,
                          unsigned short* __restrict__ W2t) {
    const float* W = blockIdx.x ? W2 : W1;
    unsigned short* Wt = blockIdx.x ? W2t : W1t;
    for (int i = threadIdx.x; i < DIM * DIM; i += 256) {
        int k = i >> 7, n = i & 127;
        Wt[n * DIM + k] = f2bf(W[i]);
    }
}

// ---------------------------------------------------------------------------
// bf16 MFMA GEMM: C(M x 128) = A(M x 128) @ B(128 x 128), B given transposed
// [n][k]. M-tile 64 (1 row-tile of 16 per wave), full B in LDS, acc 8 x
// float4 = 32 VGPRs. Single barrier before K-loop (LDS read-only after).
// 16x16x32 frag: A lane m=lane&15 holds k=(lane>>4)*8+j (b128 contiguous);
// C/D: col=lane&15, row=(lane>>4)*4+reg.
// RELU path: out = bf16(relu(c+bias)). STATS path: out f32->bf16 store + BN
// column sum/sumsq fused (LDS alias of As after barrier).
// ---------------------------------------------------------------------------
template <bool RELU, bool STATS>
__global__ __launch_bounds__(256) void mfma_gemm(
    const unsigned short* __restrict__ A,    // M_PAD x 128 bf16
    const unsigned short* __restrict__ Bt,   // 128 x 128 bf16, [n][k]
    const float* __restrict__ bias,
    unsigned short* __restrict__ outb,       // M_PAD x 128 bf16
    float* __restrict__ gstats) {
    __shared__ unsigned short As[M_TILE * LPITCH];   // 17408 B
    __shared__ unsigned short Bs[DIM * LPITCH];      // 34816 B
    int t = threadIdx.x;
    int row0 = blockIdx.x * M_TILE;

#pragma unroll
    for (int i = 0; i < 4; ++i) {            // A: 64 rows x 16 chunks of 8 bf16
        int ch = t + 256 * i;
        int r = ch >> 4, cc = ch & 15;
        *(uint4*)(&As[r * LPITCH + cc * 8]) =
            *(const uint4*)(&A[(size_t)(row0 + r) * DIM + cc * 8]);
    }
#pragma unroll
    for (int i = 0; i < 8; ++i) {            // B: 128 n-rows x 16 chunks
        int ch = t + 256 * i;
        int n = ch >> 4, cc = ch & 15;
        *(uint4*)(&Bs[n * LPITCH + cc * 8]) =
            *(const uint4*)(&Bt[n * DIM + cc * 8]);
    }
    __syncthreads();

    int lane = t & 63, wv = t >> 6;
    int m = lane & 15, g = lane >> 4;
    floatx4 acc[8] = {};
#pragma unroll
    for (int kc = 0; kc < 4; ++kc) {
        short8 a = *(const short8*)(&As[(wv * 16 + m) * LPITCH + kc * 32 + g * 8]);
#pragma unroll
        for (int tt = 0; tt < 8; ++tt) {
            short8 b = *(const short8*)(&Bs[(tt * 16 + m) * LPITCH + kc * 32 + g * 8]);
            acc[tt] = __builtin_amdgcn_mfma_f32_16x16x32_bf16(a, b, acc[tt], 0, 0, 0);
        }
    }

    if (RELU) {
#pragma unroll
        for (int tt = 0; tt < 8; ++tt) {
            int col = tt * 16 + m;
            float bv = bias[col];
#pragma unroll
            for (int j = 0; j < 4; ++j) {
                int row = row0 + wv * 16 + g * 4 + j;
                float v = fmaxf(acc[tt][j] + bv, 0.f);
                outb[(size_t)row * DIM + col] = f2bf(v);  // pad rows: benign
            }
        }
    }
    if (STATS) {
        float* csum = (float*)As;            // alias A-tile after barrier
        float* csq = csum + DIM;
        __syncthreads();                     // all LDS frag reads complete
        if (t < DIM) { csum[t] = 0.f; csq[t] = 0.f; }
        __syncthreads();
#pragma unroll
        for (int tt = 0; tt < 8; ++tt) {
            int col = tt * 16 + m;
            float bv = bias[col];
            float s = 0.f, q = 0.f;
#pragma unroll
            for (int j = 0; j < 4; ++j) {
                int row = row0 + wv * 16 + g * 4 + j;
                float v = acc[tt][j] + bv;
                outb[(size_t)row * DIM + col] = f2bf(v);
                if (row < N_NODES) { s += v; q += v * v; }
            }
            atomicAdd(&csum[col], s);
            atomicAdd(&csq[col], q);
        }
        __syncthreads();
        if (t < DIM) {
            atomicAdd(&gstats[t], csum[t]);
            atomicAdd(&gstats[DIM + t], csq[t]);
        }
    }
}

__global__ void finalize_stats(float* stats, const float* gamma,
                               const float* beta) {
    int t = threadIdx.x;                     // 128 threads
    float mean = stats[t] * (1.0f / N_NODES);
    float m2 = stats[DIM + t] * (1.0f / N_NODES);
    float var = m2 - mean * mean;
    float inv = rsqrtf(var + EPS_BN);
    float sc = gamma[t] * inv;
    float sh = beta[t] - mean * sc;
    stats[t] = sc;
    stats[DIM + t] = sh;
}

__global__ void bn_apply(const unsigned short* __restrict__ H2,
                         const float* __restrict__ stats,
                         float* __restrict__ out) {
    int i = blockIdx.x * 256 + threadIdx.x;  // one group of 4 cols
    int j4 = i & 31;
    ushort4 hv = ((const ushort4*)H2)[i];
    float4 sc = ((const float4*)stats)[j4];
    float4 sh = ((const float4*)(stats + DIM))[j4];
    float4 o;
    o.x = bf2f(hv.x) * sc.x + sh.x;
    o.y = bf2f(hv.y) * sc.y + sh.y;
    o.z = bf2f(hv.z) * sc.z + sh.z;
    o.w = bf2f(hv.w) * sc.w + sh.w;
    ((float4*)out)[i] = o;
}

// ---------------------------------------------------------------------------
extern "C" void kernel_launch(void* const* d_in, const int* in_sizes, int n_in,
                              void* d_out, int out_size, void* d_ws,
                              size_t ws_size, hipStream_t stream) {
    (void)in_sizes; (void)n_in; (void)out_size; (void)ws_size;
    const float* x     = (const float*)d_in[0];
    const void*  eidx  = d_in[1];
    const float* W1    = (const float*)d_in[2];
    const float* b1    = (const float*)d_in[3];
    const float* W2    = (const float*)d_in[4];
    const float* b2    = (const float*)d_in[5];
    const float* gamma = (const float*)d_in[6];
    const float* beta  = (const float*)d_in[7];
    float* out = (float*)d_out;

    char* p = (char*)d_ws;
    auto alloc = [&](size_t bytes) {
        char* r = p;
        p += (bytes + 255) & ~(size_t)255;
        return r;
    };
    unsigned short* Hbf  = (unsigned short*)alloc((size_t)M_PAD * DIM * 2); // 25.6MB
    unsigned short* h1bf = (unsigned short*)alloc((size_t)M_PAD * DIM * 2); // 25.6MB
    unsigned short* h2bf = Hbf;   // alias: Hbf dead after gemm1 staging
    uint2* pairs  = (uint2*)alloc((size_t)N_EDGES * 8);                     // 12.8MB
    int*   cols   = (int*)alloc((size_t)N_EDGES * 4);                       // 6.4MB
    int*   rowst  = (int*)alloc((size_t)(N_NODES + 1) * 4);
    int*   bcnt   = (int*)alloc(NB * 4);
    int*   bstart = (int*)alloc((NB + 1) * 4);
    int*   bcur   = (int*)alloc(NB * 4);
    unsigned short* W1t = (unsigned short*)alloc(DIM * DIM * 2);
    unsigned short* W2t = (unsigned short*)alloc(DIM * DIM * 2);
    float* gstats = (float*)alloc(2 * DIM * 4);
    int*   flag   = (int*)alloc(16);

    hipMemsetAsync(bcnt, 0, NB * 4, stream);
    hipMemsetAsync(gstats, 0, 2 * DIM * 4, stream);

    convert_w<<<2, 256, 0, stream>>>(W1, W2, W1t, W2t);
    detect_dtype<<<1, 1, 0, stream>>>((const int*)eidx, flag);
    bucket_hist<<<NB, 256, 0, stream>>>(eidx, flag, bcnt);
    scan512<<<1, NB, 0, stream>>>(bcnt, bstart, bcur, rowst);
    bin_scatter<<<NB, 256, 0, stream>>>(eidx, flag, bcur, pairs);
    build_csr<<<NB, 256, 0, stream>>>(pairs, bstart, rowst, cols);

    agg_kernel<<<N_NODES / 4, 256, 0, stream>>>(x, rowst, cols, Hbf);

    int gblocks = M_PAD / M_TILE;            // 1563
    mfma_gemm<true, false><<<gblocks, 256, 0, stream>>>(Hbf, W1t, b1, h1bf,
                                                        nullptr);
    mfma_gemm<false, true><<<gblocks, 256, 0, stream>>>(h1bf, W2t, b2, h2bf,
                                                        gstats);
    finalize_stats<<<1, 128, 0, stream>>>(gstats, gamma, beta);
    bn_apply<<<(N_NODES * DIM / 4) / 256, 256, 0, stream>>>(h2bf, gstats, out);
}

// Round 4
// 350.294 us; speedup vs baseline: 1.8399x; 1.1320x over previous
//
#include <hip/hip_runtime.h>

#define N_NODES 100000
#define N_EDGES 1600000
#define DIM     128
#define EPS_BN  1e-5f
#define NB      512      // coarse buckets
#define NPB     196      // nodes per bucket (512*196 >= 100000)
#define EPB     3125     // edges per block in binning (512*3125 == N_EDGES)
#define CAP     4096     // LDS col staging capacity in build_csr
#define M_TILE  64
#define M_PAD   100032   // 1563 * 64
#define LPITCH  136      // LDS pitch in bf16 units (272B = 17*16B, b128-aligned)

typedef __attribute__((ext_vector_type(8))) short short8;
typedef __attribute__((ext_vector_type(4))) float floatx4;

__device__ __forceinline__ unsigned short f2bf(float f) {   // RNE bf16 bits
    unsigned u = __float_as_uint(f);
    return (unsigned short)((u + 0x7FFF + ((u >> 16) & 1)) >> 16);
}
__device__ __forceinline__ float bf2f(unsigned short b) {
    return __uint_as_float((unsigned)b << 16);
}

// ---------------------------------------------------------------------------
// edge_index dtype detector (int64 layout => odd int32 words all zero),
// parallel across one wave.
// ---------------------------------------------------------------------------
__global__ void detect_dtype(const int* raw, int* flag) {
    int v = raw[2 * threadIdx.x + 1];        // 64 threads
    unsigned long long b = __ballot(v != 0);
    if (threadIdx.x == 0) *flag = (b == 0ULL) ? 1 : 0;
}

__device__ __forceinline__ int load_row(const void* eidx, int is64, int e) {
    if (is64) return (int)((const long long*)eidx)[e];
    return ((const int*)eidx)[e];
}
__device__ __forceinline__ int load_col(const void* eidx, int is64, int e) {
    if (is64) return (int)((const long long*)eidx)[N_EDGES + e];
    return ((const int*)eidx)[N_EDGES + e];
}

// ---------------------------------------------------------------------------
// CSR build via 2-level counting sort (all fine scatter in LDS)
// ---------------------------------------------------------------------------
__global__ __launch_bounds__(256) void bucket_hist(const void* eidx,
                                                   const int* flag,
                                                   int* bcnt) {
    __shared__ int lh[NB];
    for (int i = threadIdx.x; i < NB; i += 256) lh[i] = 0;
    __syncthreads();
    int is64 = *flag;
    int base = blockIdx.x * EPB;
    for (int i = threadIdx.x; i < EPB; i += 256) {
        int r = load_row(eidx, is64, base + i);
        atomicAdd(&lh[r / NPB], 1);
    }
    __syncthreads();
    for (int i = threadIdx.x; i < NB; i += 256)
        if (lh[i]) atomicAdd(&bcnt[i], lh[i]);
}

__global__ void scan512(const int* bcnt, int* bstart, int* bcur, int* rowst) {
    __shared__ int tmp[NB];
    int t = threadIdx.x;
    int v = bcnt[t];
    tmp[t] = v;
    __syncthreads();
    for (int off = 1; off < NB; off <<= 1) {
        int a = (t >= off) ? tmp[t - off] : 0;
        __syncthreads();
        tmp[t] += a;
        __syncthreads();
    }
    bstart[t] = tmp[t] - v;
    bcur[t]   = tmp[t] - v;
    if (t == NB - 1) { bstart[NB] = N_EDGES; rowst[N_NODES] = N_EDGES; }
}

__global__ __launch_bounds__(256) void bin_scatter(const void* eidx,
                                                   const int* flag, int* bcur,
                                                   uint2* pairs) {
    __shared__ int lh[NB];
    __shared__ int lbase[NB];
    for (int i = threadIdx.x; i < NB; i += 256) lh[i] = 0;
    __syncthreads();
    int is64 = *flag;
    int base = blockIdx.x * EPB;
    for (int i = threadIdx.x; i < EPB; i += 256) {
        int r = load_row(eidx, is64, base + i);
        atomicAdd(&lh[r / NPB], 1);
    }
    __syncthreads();
    for (int i = threadIdx.x; i < NB; i += 256) {
        int c = lh[i];
        lbase[i] = c ? atomicAdd(&bcur[i], c) : 0;
        lh[i] = 0;
    }
    __syncthreads();
    for (int i = threadIdx.x; i < EPB; i += 256) {
        int r = load_row(eidx, is64, base + i);
        int c = load_col(eidx, is64, base + i);
        int b = r / NPB;
        int pos = lbase[b] + atomicAdd(&lh[b], 1);
        pairs[pos] = make_uint2((unsigned)r, (unsigned)c);
    }
}

__global__ __launch_bounds__(256) void build_csr(const uint2* __restrict__ pairs,
                                                 const int* __restrict__ bstart,
                                                 int* __restrict__ rowst,
                                                 int* __restrict__ cols) {
    __shared__ int hist[256];
    __shared__ int excl[256];
    __shared__ int cur[256];
    __shared__ int colbuf[CAP];
    int b = blockIdx.x;
    int node0 = b * NPB;
    int nn = N_NODES - node0;
    if (nn <= 0) return;
    if (nn > NPB) nn = NPB;
    int s = bstart[b], e = bstart[b + 1];
    int cnt = e - s;
    int t = threadIdx.x;
    hist[t] = 0;
    __syncthreads();
    for (int i = t; i < cnt; i += 256)
        atomicAdd(&hist[(int)pairs[s + i].x - node0], 1);
    __syncthreads();
    int v = hist[t];
    excl[t] = v;
    __syncthreads();
    for (int off = 1; off < 256; off <<= 1) {
        int a = (t >= off) ? excl[t - off] : 0;
        __syncthreads();
        excl[t] += a;
        __syncthreads();
    }
    int ex = excl[t] - v;
    if (t < nn) rowst[node0 + t] = s + ex;
    cur[t] = ex;
    __syncthreads();
    if (cnt <= CAP) {
        for (int i = t; i < cnt; i += 256) {
            uint2 pr = pairs[s + i];
            int pos = atomicAdd(&cur[(int)pr.x - node0], 1);
            colbuf[pos] = (int)pr.y;
        }
        __syncthreads();
        for (int i = t; i < cnt; i += 256) cols[s + i] = colbuf[i];
    } else {
        for (int i = t; i < cnt; i += 256) {
            uint2 pr = pairs[s + i];
            int pos = atomicAdd(&cur[(int)pr.x - node0], 1);
            cols[s + pos] = (int)pr.y;
        }
    }
}

// ---------------------------------------------------------------------------
// x (f32) -> xb (bf16), row-major. 77 MB traffic, ~13 us.
// ---------------------------------------------------------------------------
__global__ void xconv(const float* __restrict__ x,
                      unsigned short* __restrict__ xb) {
    int i = blockIdx.x * 256 + threadIdx.x;
    float4 v = ((const float4*)x)[i];
    ushort4 o;
    o.x = f2bf(v.x); o.y = f2bf(v.y); o.z = f2bf(v.z); o.w = f2bf(v.w);
    ((ushort4*)xb)[i] = o;
}

// ---------------------------------------------------------------------------
// Aggregation + residual: Hbf[n] = bf16(x[n] + sum xb[c]).
// One wave per node. Neighbor ids via wave-uniform (scalar) loads, neighbor
// rows in bf16 (256B, one uint/lane), 8 independent row loads in flight.
// Self/residual row read in f32.
// ---------------------------------------------------------------------------
__global__ __launch_bounds__(256) void agg_kernel(
    const float* __restrict__ x, const unsigned short* __restrict__ xb,
    const int* __restrict__ row_start, const int* __restrict__ cols,
    unsigned short* __restrict__ Hbf) {
    int wave = threadIdx.x >> 6;
    int lane = threadIdx.x & 63;
    int node = blockIdx.x * 4 + wave;
    float2 acc = ((const float2*)(x + (size_t)node * DIM))[lane];
    int s = row_start[node], e = row_start[node + 1];
    s = __builtin_amdgcn_readfirstlane(s);
    e = __builtin_amdgcn_readfirstlane(e);
    const unsigned* xbw = (const unsigned*)xb;     // 64 words per row
    int j = s;
    for (; j + 8 <= e; j += 8) {
        unsigned pw[8];
#pragma unroll
        for (int u = 0; u < 8; ++u) {
            int c = cols[j + u];                   // wave-uniform -> scalar
            pw[u] = xbw[(size_t)c * 64 + lane];
        }
#pragma unroll
        for (int u = 0; u < 8; ++u) {
            acc.x += __uint_as_float(pw[u] << 16);
            acc.y += __uint_as_float(pw[u] & 0xffff0000u);
        }
    }
    for (; j < e; ++j) {
        unsigned p = xbw[(size_t)cols[j] * 64 + lane];
        acc.x += __uint_as_float(p << 16);
        acc.y += __uint_as_float(p & 0xffff0000u);
    }
    unsigned pack = (unsigned)f2bf(acc.x) | ((unsigned)f2bf(acc.y) << 16);
    ((unsigned*)Hbf)[(size_t)node * 64 + lane] = pack;
}

// ---------------------------------------------------------------------------
// W (128x128 f32, [k][n]) -> bf16 transposed [n][k]. Tiny; L2-resident.
// ---------------------------------------------------------------------------
__global__ void convert_w(const float* __restrict__ W1,
                          const float* __restrict__ W2,
                          unsigned short* __restrict__ W1t,
                          unsigned short* __restrict__ W2t) {
    const float* W = blockIdx.x ? W2 : W1;
    unsigned short* Wt = blockIdx.x ? W2t : W1t;
    for (int i = threadIdx.x; i < DIM * DIM; i += 256) {
        int k = i >> 7, n = i & 127;
        Wt[n * DIM + k] = f2bf(W[i]);
    }
}

// ---------------------------------------------------------------------------
// bf16 MFMA GEMM (see R3 notes). 64-row M-tile, full B in LDS, acc 8xfloat4.
// ---------------------------------------------------------------------------
template <bool RELU, bool STATS>
__global__ __launch_bounds__(256) void mfma_gemm(
    const unsigned short* __restrict__ A,    // M_PAD x 128 bf16
    const unsigned short* __restrict__ Bt,   // 128 x 128 bf16, [n][k]
    const float* __restrict__ bias,
    unsigned short* __restrict__ outb,       // M_PAD x 128 bf16
    float* __restrict__ gstats) {
    __shared__ unsigned short As[M_TILE * LPITCH];   // 17408 B
    __shared__ unsigned short Bs[DIM * LPITCH];      // 34816 B
    int t = threadIdx.x;
    int row0 = blockIdx.x * M_TILE;

#pragma unroll
    for (int i = 0; i < 4; ++i) {            // A: 64 rows x 16 chunks of 8 bf16
        int ch = t + 256 * i;
        int r = ch >> 4, cc = ch & 15;
        *(uint4*)(&As[r * LPITCH + cc * 8]) =
            *(const uint4*)(&A[(size_t)(row0 + r) * DIM + cc * 8]);
    }
#pragma unroll
    for (int i = 0; i < 8; ++i) {            // B: 128 n-rows x 16 chunks
        int ch = t + 256 * i;
        int n = ch >> 4, cc = ch & 15;
        *(uint4*)(&Bs[n * LPITCH + cc * 8]) =
            *(const uint4*)(&Bt[n * DIM + cc * 8]);
    }
    __syncthreads();

    int lane = t & 63, wv = t >> 6;
    int m = lane & 15, g = lane >> 4;
    floatx4 acc[8] = {};
#pragma unroll
    for (int kc = 0; kc < 4; ++kc) {
        short8 a = *(const short8*)(&As[(wv * 16 + m) * LPITCH + kc * 32 + g * 8]);
#pragma unroll
        for (int tt = 0; tt < 8; ++tt) {
            short8 b = *(const short8*)(&Bs[(tt * 16 + m) * LPITCH + kc * 32 + g * 8]);
            acc[tt] = __builtin_amdgcn_mfma_f32_16x16x32_bf16(a, b, acc[tt], 0, 0, 0);
        }
    }

    if (RELU) {
#pragma unroll
        for (int tt = 0; tt < 8; ++tt) {
            int col = tt * 16 + m;
            float bv = bias[col];
#pragma unroll
            for (int j = 0; j < 4; ++j) {
                int row = row0 + wv * 16 + g * 4 + j;
                float v = fmaxf(acc[tt][j] + bv, 0.f);
                outb[(size_t)row * DIM + col] = f2bf(v);
            }
        }
    }
    if (STATS) {
        float* csum = (float*)As;            // alias A-tile after barrier
        float* csq = csum + DIM;
        __syncthreads();
        if (t < DIM) { csum[t] = 0.f; csq[t] = 0.f; }
        __syncthreads();
#pragma unroll
        for (int tt = 0; tt < 8; ++tt) {
            int col = tt * 16 + m;
            float bv = bias[col];
            float s = 0.f, q = 0.f;
#pragma unroll
            for (int j = 0; j < 4; ++j) {
                int row = row0 + wv * 16 + g * 4 + j;
                float v = acc[tt][j] + bv;
                outb[(size_t)row * DIM + col] = f2bf(v);
                if (row < N_NODES) { s += v; q += v * v; }
            }
            atomicAdd(&csum[col], s);
            atomicAdd(&csq[col], q);
        }
        __syncthreads();
        if (t < DIM) {
            atomicAdd(&gstats[t], csum[t]);
            atomicAdd(&gstats[DIM + t], csq[t]);
        }
    }
}

// ---------------------------------------------------------------------------
// BN finalize (redundant per block, removes a dispatch) + apply.
// ---------------------------------------------------------------------------
__global__ __launch_bounds__(256) void bn_apply(
    const unsigned short* __restrict__ H2, const float* __restrict__ gstats,
    const float* __restrict__ gamma, const float* __restrict__ beta,
    float* __restrict__ out) {
    __shared__ float sc_s[DIM], sh_s[DIM];
    int t = threadIdx.x;
    if (t < DIM) {
        float mean = gstats[t] * (1.0f / N_NODES);
        float m2 = gstats[DIM + t] * (1.0f / N_NODES);
        float var = m2 - mean * mean;
        float inv = rsqrtf(var + EPS_BN);
        float sc = gamma[t] * inv;
        sc_s[t] = sc;
        sh_s[t] = beta[t] - mean * sc;
    }
    __syncthreads();
    int i = blockIdx.x * 256 + t;
    int j4 = (i & 31) * 4;
    ushort4 hv = ((const ushort4*)H2)[i];
    float4 o;
    o.x = bf2f(hv.x) * sc_s[j4 + 0] + sh_s[j4 + 0];
    o.y = bf2f(hv.y) * sc_s[j4 + 1] + sh_s[j4 + 1];
    o.z = bf2f(hv.z) * sc_s[j4 + 2] + sh_s[j4 + 2];
    o.w = bf2f(hv.w) * sc_s[j4 + 3] + sh_s[j4 + 3];
    ((float4*)out)[i] = o;
}

// ---------------------------------------------------------------------------
extern "C" void kernel_launch(void* const* d_in, const int* in_sizes, int n_in,
                              void* d_out, int out_size, void* d_ws,
                              size_t ws_size, hipStream_t stream) {
    (void)in_sizes; (void)n_in; (void)out_size; (void)ws_size;
    const float* x     = (const float*)d_in[0];
    const void*  eidx  = d_in[1];
    const float* W1    = (const float*)d_in[2];
    const float* b1    = (const float*)d_in[3];
    const float* W2    = (const float*)d_in[4];
    const float* b2    = (const float*)d_in[5];
    const float* gamma = (const float*)d_in[6];
    const float* beta  = (const float*)d_in[7];
    float* out = (float*)d_out;

    char* p = (char*)d_ws;
    auto alloc = [&](size_t bytes) {
        char* r = p;
        p += (bytes + 255) & ~(size_t)255;
        return r;
    };
    unsigned short* Hbf  = (unsigned short*)alloc((size_t)M_PAD * DIM * 2); // 25.6MB
    unsigned short* h1bf = (unsigned short*)alloc((size_t)M_PAD * DIM * 2); // 25.6MB
    unsigned short* h2bf = Hbf;   // alias: Hbf dead after gemm1 staging
    // xb aliases pairs: pairs dead after build_csr, xconv runs after it.
    unsigned short* xb = (unsigned short*)alloc((size_t)N_NODES * DIM * 2); // 25.6MB
    uint2* pairs  = (uint2*)xb;
    int*   cols   = (int*)alloc((size_t)N_EDGES * 4);                       // 6.4MB
    int*   rowst  = (int*)alloc((size_t)(N_NODES + 1) * 4);
    int*   bcnt   = (int*)alloc(NB * 4);
    int*   bstart = (int*)alloc((NB + 1) * 4);
    int*   bcur   = (int*)alloc(NB * 4);
    unsigned short* W1t = (unsigned short*)alloc(DIM * DIM * 2);
    unsigned short* W2t = (unsigned short*)alloc(DIM * DIM * 2);
    float* gstats = (float*)alloc(2 * DIM * 4);
    int*   flag   = (int*)alloc(16);

    hipMemsetAsync(bcnt, 0, NB * 4, stream);
    hipMemsetAsync(gstats, 0, 2 * DIM * 4, stream);

    convert_w<<<2, 256, 0, stream>>>(W1, W2, W1t, W2t);
    detect_dtype<<<1, 64, 0, stream>>>((const int*)eidx, flag);
    bucket_hist<<<NB, 256, 0, stream>>>(eidx, flag, bcnt);
    scan512<<<1, NB, 0, stream>>>(bcnt, bstart, bcur, rowst);
    bin_scatter<<<NB, 256, 0, stream>>>(eidx, flag, bcur, pairs);
    build_csr<<<NB, 256, 0, stream>>>(pairs, bstart, rowst, cols);

    xconv<<<N_NODES * DIM / 4 / 256, 256, 0, stream>>>(x, xb);
    agg_kernel<<<N_NODES / 4, 256, 0, stream>>>(x, xb, rowst, cols, Hbf);

    int gblocks = M_PAD / M_TILE;            // 1563
    mfma_gemm<true, false><<<gblocks, 256, 0, stream>>>(Hbf, W1t, b1, h1bf,
                                                        nullptr);
    mfma_gemm<false, true><<<gblocks, 256, 0, stream>>>(h1bf, W2t, b2, h2bf,
                                                        gstats);
    bn_apply<<<(N_NODES * DIM / 4) / 256, 256, 0, stream>>>(h2bf, gstats,
                                                            gamma, beta, out);
}

// Round 5
// 330.674 us; speedup vs baseline: 1.9491x; 1.0593x over previous
//
#include <hip/hip_runtime.h>

#define N_NODES 100000
#define N_EDGES 1600000
#define DIM     128
#define EPS_BN  1e-5f
#define NB      512      // coarse buckets
#define NPB     196      // nodes per bucket (512*196 >= 100000)
#define EPB     3125     // edges per block in binning (512*3125 == N_EDGES)
#define CAP     4096     // LDS col staging capacity in build_csr
#define M_TILE  64
#define M_PAD   100032   // 1563 * 64
#define LPITCH  136      // LDS pitch in bf16 units (272B = 17*16B, b128-aligned)

typedef __attribute__((ext_vector_type(8))) short short8;
typedef __attribute__((ext_vector_type(4))) float floatx4;

__device__ __forceinline__ unsigned short f2bf(float f) {   // RNE bf16 bits
    unsigned u = __float_as_uint(f);
    return (unsigned short)((u + 0x7FFF + ((u >> 16) & 1)) >> 16);
}
__device__ __forceinline__ float bf2f(unsigned short b) {
    return __uint_as_float((unsigned)b << 16);
}

// ---------------------------------------------------------------------------
// In-kernel edge dtype detection: int64 layout => odd int32 words all zero.
// Every wave reads the same 64 words -> identical (wave-uniform) result.
// ---------------------------------------------------------------------------
__device__ __forceinline__ int detect64(const void* eidx) {
    int v = ((const int*)eidx)[2 * (threadIdx.x & 63) + 1];
    unsigned long long b = __ballot(v != 0);
    return (b == 0ULL) ? 1 : 0;
}

__device__ __forceinline__ int load_row(const void* eidx, int is64, int e) {
    if (is64) return (int)((const long long*)eidx)[e];
    return ((const int*)eidx)[e];
}
__device__ __forceinline__ int load_col(const void* eidx, int is64, int e) {
    if (is64) return (int)((const long long*)eidx)[N_EDGES + e];
    return ((const int*)eidx)[N_EDGES + e];
}

// ---------------------------------------------------------------------------
// CSR build via 2-level counting sort (all fine scatter in LDS)
// ---------------------------------------------------------------------------
__global__ __launch_bounds__(256) void bucket_hist(const void* eidx,
                                                   int* bcnt) {
    __shared__ int lh[NB];
    for (int i = threadIdx.x; i < NB; i += 256) lh[i] = 0;
    int is64 = detect64(eidx);
    __syncthreads();
    int base = blockIdx.x * EPB;
    for (int i = threadIdx.x; i < EPB; i += 256) {
        int r = load_row(eidx, is64, base + i);
        atomicAdd(&lh[r / NPB], 1);
    }
    __syncthreads();
    for (int i = threadIdx.x; i < NB; i += 256)
        if (lh[i]) atomicAdd(&bcnt[i], lh[i]);
}

__global__ void scan512(const int* bcnt, int* bstart, int* bcur, int* rowst) {
    __shared__ int tmp[NB];
    int t = threadIdx.x;
    int v = bcnt[t];
    tmp[t] = v;
    __syncthreads();
    for (int off = 1; off < NB; off <<= 1) {
        int a = (t >= off) ? tmp[t - off] : 0;
        __syncthreads();
        tmp[t] += a;
        __syncthreads();
    }
    bstart[t] = tmp[t] - v;
    bcur[t]   = tmp[t] - v;
    if (t == NB - 1) { bstart[NB] = N_EDGES; rowst[N_NODES] = N_EDGES; }
}

__global__ __launch_bounds__(256) void bin_scatter(const void* eidx, int* bcur,
                                                   uint2* pairs) {
    __shared__ int lh[NB];
    __shared__ int lbase[NB];
    for (int i = threadIdx.x; i < NB; i += 256) lh[i] = 0;
    int is64 = detect64(eidx);
    __syncthreads();
    int base = blockIdx.x * EPB;
    for (int i = threadIdx.x; i < EPB; i += 256) {
        int r = load_row(eidx, is64, base + i);
        atomicAdd(&lh[r / NPB], 1);
    }
    __syncthreads();
    for (int i = threadIdx.x; i < NB; i += 256) {
        int c = lh[i];
        lbase[i] = c ? atomicAdd(&bcur[i], c) : 0;
        lh[i] = 0;
    }
    __syncthreads();
    for (int i = threadIdx.x; i < EPB; i += 256) {
        int r = load_row(eidx, is64, base + i);
        int c = load_col(eidx, is64, base + i);
        int b = r / NPB;
        int pos = lbase[b] + atomicAdd(&lh[b], 1);
        pairs[pos] = make_uint2((unsigned)r, (unsigned)c);
    }
}

__global__ __launch_bounds__(256) void build_csr(const uint2* __restrict__ pairs,
                                                 const int* __restrict__ bstart,
                                                 int* __restrict__ rowst,
                                                 int* __restrict__ cols) {
    __shared__ int hist[256];
    __shared__ int excl[256];
    __shared__ int cur[256];
    __shared__ int colbuf[CAP];
    int b = blockIdx.x;
    int node0 = b * NPB;
    int nn = N_NODES - node0;
    if (nn <= 0) return;
    if (nn > NPB) nn = NPB;
    int s = bstart[b], e = bstart[b + 1];
    int cnt = e - s;
    int t = threadIdx.x;
    hist[t] = 0;
    __syncthreads();
    for (int i = t; i < cnt; i += 256)
        atomicAdd(&hist[(int)pairs[s + i].x - node0], 1);
    __syncthreads();
    int v = hist[t];
    excl[t] = v;
    __syncthreads();
    for (int off = 1; off < 256; off <<= 1) {
        int a = (t >= off) ? excl[t - off] : 0;
        __syncthreads();
        excl[t] += a;
        __syncthreads();
    }
    int ex = excl[t] - v;
    if (t < nn) rowst[node0 + t] = s + ex;
    cur[t] = ex;
    __syncthreads();
    if (cnt <= CAP) {
        for (int i = t; i < cnt; i += 256) {
            uint2 pr = pairs[s + i];
            int pos = atomicAdd(&cur[(int)pr.x - node0], 1);
            colbuf[pos] = (int)pr.y;
        }
        __syncthreads();
        for (int i = t; i < cnt; i += 256) cols[s + i] = colbuf[i];
    } else {
        for (int i = t; i < cnt; i += 256) {
            uint2 pr = pairs[s + i];
            int pos = atomicAdd(&cur[(int)pr.x - node0], 1);
            cols[s + pos] = (int)pr.y;
        }
    }
}

// ---------------------------------------------------------------------------
// x (f32) -> xb (bf16), row-major.
// ---------------------------------------------------------------------------
__global__ void xconv(const float* __restrict__ x,
                      unsigned short* __restrict__ xb) {
    int i = blockIdx.x * 256 + threadIdx.x;
    float4 v = ((const float4*)x)[i];
    ushort4 o;
    o.x = f2bf(v.x); o.y = f2bf(v.y); o.z = f2bf(v.z); o.w = f2bf(v.w);
    ((ushort4*)xb)[i] = o;
}

// ---------------------------------------------------------------------------
// Aggregation + residual, all-bf16 gather: Hbf[n] = bf16(xb[n] + sum xb[c]).
// One wave per node; 16 independent row loads in flight per chunk.
// ---------------------------------------------------------------------------
__global__ __launch_bounds__(256) void agg_kernel(
    const unsigned short* __restrict__ xb,
    const int* __restrict__ row_start, const int* __restrict__ cols,
    unsigned short* __restrict__ Hbf) {
    int wave = threadIdx.x >> 6;
    int lane = threadIdx.x & 63;
    int node = blockIdx.x * 4 + wave;
    const unsigned* xbw = (const unsigned*)xb;     // 64 words per row
    unsigned selfw = xbw[(size_t)node * 64 + lane];
    float2 acc;
    acc.x = __uint_as_float(selfw << 16);
    acc.y = __uint_as_float(selfw & 0xffff0000u);
    int s = row_start[node], e = row_start[node + 1];
    s = __builtin_amdgcn_readfirstlane(s);
    e = __builtin_amdgcn_readfirstlane(e);
    int j = s;
    for (; j + 16 <= e; j += 16) {
        unsigned pw[16];
#pragma unroll
        for (int u = 0; u < 16; ++u) {
            int c = cols[j + u];                   // wave-uniform -> scalar
            pw[u] = xbw[(size_t)c * 64 + lane];
        }
#pragma unroll
        for (int u = 0; u < 16; ++u) {
            acc.x += __uint_as_float(pw[u] << 16);
            acc.y += __uint_as_float(pw[u] & 0xffff0000u);
        }
    }
    for (; j + 4 <= e; j += 4) {
        unsigned pw[4];
#pragma unroll
        for (int u = 0; u < 4; ++u) {
            int c = cols[j + u];
            pw[u] = xbw[(size_t)c * 64 + lane];
        }
#pragma unroll
        for (int u = 0; u < 4; ++u) {
            acc.x += __uint_as_float(pw[u] << 16);
            acc.y += __uint_as_float(pw[u] & 0xffff0000u);
        }
    }
    for (; j < e; ++j) {
        unsigned p = xbw[(size_t)cols[j] * 64 + lane];
        acc.x += __uint_as_float(p << 16);
        acc.y += __uint_as_float(p & 0xffff0000u);
    }
    unsigned pack = (unsigned)f2bf(acc.x) | ((unsigned)f2bf(acc.y) << 16);
    ((unsigned*)Hbf)[(size_t)node * 64 + lane] = pack;
}

// ---------------------------------------------------------------------------
// W (128x128 f32, [k][n]) -> bf16 transposed [n][k]. Tiny; L2-resident.
// ---------------------------------------------------------------------------
__global__ void convert_w(const float* __restrict__ W1,
                          const float* __restrict__ W2,
                          unsigned short* __restrict__ W1t,
                          unsigned short* __restrict__ W2t) {
    const float* W = blockIdx.x ? W2 : W1;
    unsigned short* Wt = blockIdx.x ? W2t : W1t;
    for (int i = threadIdx.x; i < DIM * DIM; i += 256) {
        int k = i >> 7, n = i & 127;
        Wt[n * DIM + k] = f2bf(W[i]);
    }
}

// ---------------------------------------------------------------------------
// Fused MLP: h2 = (relu(A@W1+b1))@W2 + b2, per 64-row tile, one kernel.
// Phase 1: A,W1 in LDS -> acc1. Barrier. h1(bf16) round-trips through As
// (C-layout -> A-layout), W2 overwrites Bs (global loads issued before the
// LDS writes to hide latency). Phase 2: acc2 -> h2 + fused BN stats.
// LDS 52KB -> 2 blocks/CU. Frag maps (m89/m91-verified):
//   A: lane m=lane&15 holds k=(lane>>4)*8+j ; C/D: col=lane&15,
//   row=(lane>>4)*4+reg.
// ---------------------------------------------------------------------------
__global__ __launch_bounds__(256) void mlp_fused(
    const unsigned short* __restrict__ A,    // M_PAD x 128 bf16
    const unsigned short* __restrict__ B1t,  // W1^T bf16 [n][k]
    const unsigned short* __restrict__ B2t,  // W2^T bf16 [n][k]
    const float* __restrict__ bias1, const float* __restrict__ bias2,
    unsigned short* __restrict__ outb,       // M_PAD x 128 bf16
    float* __restrict__ gstats) {
    __shared__ unsigned short As[M_TILE * LPITCH];   // 17408 B
    __shared__ unsigned short Bs[DIM * LPITCH];      // 34816 B
    int t = threadIdx.x;
    int row0 = blockIdx.x * M_TILE;
    int lane = t & 63, wv = t >> 6;
    int m = lane & 15, g = lane >> 4;

#pragma unroll
    for (int i = 0; i < 4; ++i) {            // A: 64 rows x 16 chunks of 8 bf16
        int ch = t + 256 * i;
        int r = ch >> 4, cc = ch & 15;
        *(uint4*)(&As[r * LPITCH + cc * 8]) =
            *(const uint4*)(&A[(size_t)(row0 + r) * DIM + cc * 8]);
    }
#pragma unroll
    for (int i = 0; i < 8; ++i) {            // W1: 128 n-rows x 16 chunks
        int ch = t + 256 * i;
        int n = ch >> 4, cc = ch & 15;
        *(uint4*)(&Bs[n * LPITCH + cc * 8]) =
            *(const uint4*)(&B1t[n * DIM + cc * 8]);
    }
    __syncthreads();

    floatx4 acc1[8] = {};
#pragma unroll
    for (int kc = 0; kc < 4; ++kc) {
        short8 a = *(const short8*)(&As[(wv * 16 + m) * LPITCH + kc * 32 + g * 8]);
#pragma unroll
        for (int tt = 0; tt < 8; ++tt) {
            short8 b = *(const short8*)(&Bs[(tt * 16 + m) * LPITCH + kc * 32 + g * 8]);
            acc1[tt] = __builtin_amdgcn_mfma_f32_16x16x32_bf16(a, b, acc1[tt], 0, 0, 0);
        }
    }
    __syncthreads();                          // phase-1 LDS reads complete

    // issue W2 global loads early (latency hidden behind h1 LDS writes)
    uint4 wbuf[8];
#pragma unroll
    for (int i = 0; i < 8; ++i) {
        int ch = t + 256 * i;
        int n = ch >> 4, cc = ch & 15;
        wbuf[i] = *(const uint4*)(&B2t[n * DIM + cc * 8]);
    }
    // h1 = bf16(relu(acc1+b1)) scattered into As at (row,col) = A-layout src
#pragma unroll
    for (int tt = 0; tt < 8; ++tt) {
        int col = tt * 16 + m;
        float bv = bias1[col];
#pragma unroll
        for (int j = 0; j < 4; ++j) {
            int rl = wv * 16 + g * 4 + j;
            As[rl * LPITCH + col] = f2bf(fmaxf(acc1[tt][j] + bv, 0.f));
        }
    }
#pragma unroll
    for (int i = 0; i < 8; ++i) {
        int ch = t + 256 * i;
        int n = ch >> 4, cc = ch & 15;
        *(uint4*)(&Bs[n * LPITCH + cc * 8]) = wbuf[i];
    }
    __syncthreads();

    floatx4 acc2[8] = {};
#pragma unroll
    for (int kc = 0; kc < 4; ++kc) {
        short8 a = *(const short8*)(&As[(wv * 16 + m) * LPITCH + kc * 32 + g * 8]);
#pragma unroll
        for (int tt = 0; tt < 8; ++tt) {
            short8 b = *(const short8*)(&Bs[(tt * 16 + m) * LPITCH + kc * 32 + g * 8]);
            acc2[tt] = __builtin_amdgcn_mfma_f32_16x16x32_bf16(a, b, acc2[tt], 0, 0, 0);
        }
    }

    // epilogue: h2 store + BN column sums (csum/csq alias As after barrier)
    float* csum = (float*)As;
    float* csq = csum + DIM;
    __syncthreads();
    if (t < DIM) { csum[t] = 0.f; csq[t] = 0.f; }
    __syncthreads();
#pragma unroll
    for (int tt = 0; tt < 8; ++tt) {
        int col = tt * 16 + m;
        float bv = bias2[col];
        float s = 0.f, q = 0.f;
#pragma unroll
        for (int j = 0; j < 4; ++j) {
            int row = row0 + wv * 16 + g * 4 + j;
            float v = acc2[tt][j] + bv;
            outb[(size_t)row * DIM + col] = f2bf(v);
            if (row < N_NODES) { s += v; q += v * v; }
        }
        atomicAdd(&csum[col], s);
        atomicAdd(&csq[col], q);
    }
    __syncthreads();
    if (t < DIM) {
        atomicAdd(&gstats[t], csum[t]);
        atomicAdd(&gstats[DIM + t], csq[t]);
    }
}

// ---------------------------------------------------------------------------
// BN finalize (redundant per block) + apply.
// ---------------------------------------------------------------------------
__global__ __launch_bounds__(256) void bn_apply(
    const unsigned short* __restrict__ H2, const float* __restrict__ gstats,
    const float* __restrict__ gamma, const float* __restrict__ beta,
    float* __restrict__ out) {
    __shared__ float sc_s[DIM], sh_s[DIM];
    int t = threadIdx.x;
    if (t < DIM) {
        float mean = gstats[t] * (1.0f / N_NODES);
        float m2 = gstats[DIM + t] * (1.0f / N_NODES);
        float var = m2 - mean * mean;
        float inv = rsqrtf(var + EPS_BN);
        float sc = gamma[t] * inv;
        sc_s[t] = sc;
        sh_s[t] = beta[t] - mean * sc;
    }
    __syncthreads();
    int i = blockIdx.x * 256 + t;
    int j4 = (i & 31) * 4;
    ushort4 hv = ((const ushort4*)H2)[i];
    float4 o;
    o.x = bf2f(hv.x) * sc_s[j4 + 0] + sh_s[j4 + 0];
    o.y = bf2f(hv.y) * sc_s[j4 + 1] + sh_s[j4 + 1];
    o.z = bf2f(hv.z) * sc_s[j4 + 2] + sh_s[j4 + 2];
    o.w = bf2f(hv.w) * sc_s[j4 + 3] + sh_s[j4 + 3];
    ((float4*)out)[i] = o;
}

// ---------------------------------------------------------------------------
extern "C" void kernel_launch(void* const* d_in, const int* in_sizes, int n_in,
                              void* d_out, int out_size, void* d_ws,
                              size_t ws_size, hipStream_t stream) {
    (void)in_sizes; (void)n_in; (void)out_size; (void)ws_size;
    const float* x     = (const float*)d_in[0];
    const void*  eidx  = d_in[1];
    const float* W1    = (const float*)d_in[2];
    const float* b1    = (const float*)d_in[3];
    const float* W2    = (const float*)d_in[4];
    const float* b2    = (const float*)d_in[5];
    const float* gamma = (const float*)d_in[6];
    const float* beta  = (const float*)d_in[7];
    float* out = (float*)d_out;

    char* p = (char*)d_ws;
    auto alloc = [&](size_t bytes) {
        char* r = p;
        p += (bytes + 255) & ~(size_t)255;
        return r;
    };
    unsigned short* Hbf  = (unsigned short*)alloc((size_t)M_PAD * DIM * 2); // 25.6MB
    unsigned short* h2bf = (unsigned short*)alloc((size_t)M_PAD * DIM * 2); // 25.6MB
    // xb aliases pairs: pairs dead after build_csr, xconv runs after it.
    unsigned short* xb = (unsigned short*)alloc((size_t)N_NODES * DIM * 2); // 25.6MB
    uint2* pairs  = (uint2*)xb;
    int*   cols   = (int*)alloc((size_t)N_EDGES * 4);                       // 6.4MB
    int*   rowst  = (int*)alloc((size_t)(N_NODES + 1) * 4);
    int*   bcnt   = (int*)alloc(NB * 4);
    int*   bstart = (int*)alloc((NB + 1) * 4);
    int*   bcur   = (int*)alloc(NB * 4);
    unsigned short* W1t = (unsigned short*)alloc(DIM * DIM * 2);
    unsigned short* W2t = (unsigned short*)alloc(DIM * DIM * 2);
    float* gstats = (float*)alloc(2 * DIM * 4);

    hipMemsetAsync(bcnt, 0, NB * 4, stream);
    hipMemsetAsync(gstats, 0, 2 * DIM * 4, stream);

    convert_w<<<2, 256, 0, stream>>>(W1, W2, W1t, W2t);
    bucket_hist<<<NB, 256, 0, stream>>>(eidx, bcnt);
    scan512<<<1, NB, 0, stream>>>(bcnt, bstart, bcur, rowst);
    bin_scatter<<<NB, 256, 0, stream>>>(eidx, bcur, pairs);
    build_csr<<<NB, 256, 0, stream>>>(pairs, bstart, rowst, cols);

    xconv<<<N_NODES * DIM / 4 / 256, 256, 0, stream>>>(x, xb);
    agg_kernel<<<N_NODES / 4, 256, 0, stream>>>(xb, rowst, cols, Hbf);

    mlp_fused<<<M_PAD / M_TILE, 256, 0, stream>>>(Hbf, W1t, W2t, b1, b2,
                                                  h2bf, gstats);
    bn_apply<<<(N_NODES * DIM / 4) / 256, 256, 0, stream>>>(h2bf, gstats,
                                                            gamma, beta, out);
}

// Round 6
// 325.588 us; speedup vs baseline: 1.9795x; 1.0156x over previous
//
#include <hip/hip_runtime.h>

#define N_NODES 100000
#define N_EDGES 1600000
#define DIM     128
#define EPS_BN  1e-5f
#define NB      512      // coarse buckets
#define NPB     196      // nodes per bucket (512*196 >= 100000)
#define EPB     3125     // edges per block in binning (512*3125 == N_EDGES)
#define CAP     4096     // slot capacity per bucket (mean 3125, sigma~56: 17sig)
#define M_TILE  64
#define M_PAD   100032   // 1563 * 64
#define GBLK    1563     // M_PAD / M_TILE
#define LPITCH  136      // LDS pitch in bf16 units (272B = 17*16B, b128-aligned)

typedef __attribute__((ext_vector_type(8))) short short8;
typedef __attribute__((ext_vector_type(4))) float floatx4;

__device__ __forceinline__ unsigned short f2bf(float f) {   // RNE bf16 bits
    unsigned u = __float_as_uint(f);
    return (unsigned short)((u + 0x7FFF + ((u >> 16) & 1)) >> 16);
}
__device__ __forceinline__ float bf2f(unsigned short b) {
    return __uint_as_float((unsigned)b << 16);
}

// ---------------------------------------------------------------------------
// In-kernel edge dtype detection: int64 layout => odd int32 words all zero.
// Wave-uniform result (all waves read the same 64 words).
// ---------------------------------------------------------------------------
__device__ __forceinline__ int detect64(const void* eidx) {
    int v = ((const int*)eidx)[2 * (threadIdx.x & 63) + 1];
    unsigned long long b = __ballot(v != 0);
    return (b == 0ULL) ? 1 : 0;
}

__device__ __forceinline__ int load_row(const void* eidx, int is64, int e) {
    if (is64) return (int)((const long long*)eidx)[e];
    return ((const int*)eidx)[e];
}
__device__ __forceinline__ int load_col(const void* eidx, int is64, int e) {
    if (is64) return (int)((const long long*)eidx)[N_EDGES + e];
    return ((const int*)eidx)[N_EDGES + e];
}

// ---------------------------------------------------------------------------
// Single-pass binning into fixed-capacity slots: block-local LDS hist, one
// range-claim atomic per (block,bucket), then scatter (r,c) pairs in runs.
// bcur starts at 0 (memset); slot region for bucket b is slots[b*CAP ..].
// ---------------------------------------------------------------------------
__global__ __launch_bounds__(256) void bin_scatter(const void* eidx, int* bcur,
                                                   uint2* slots) {
    __shared__ int lh[NB];
    __shared__ int lbase[NB];
    for (int i = threadIdx.x; i < NB; i += 256) lh[i] = 0;
    int is64 = detect64(eidx);
    __syncthreads();
    int base = blockIdx.x * EPB;
    for (int i = threadIdx.x; i < EPB; i += 256) {
        int r = load_row(eidx, is64, base + i);
        atomicAdd(&lh[r / NPB], 1);
    }
    __syncthreads();
    for (int i = threadIdx.x; i < NB; i += 256) {
        int c = lh[i];
        lbase[i] = c ? atomicAdd(&bcur[i], c) : 0;
        lh[i] = 0;
    }
    __syncthreads();
    for (int i = threadIdx.x; i < EPB; i += 256) {
        int r = load_row(eidx, is64, base + i);
        int c = load_col(eidx, is64, base + i);
        int b = r / NPB;
        int pos = lbase[b] + atomicAdd(&lh[b], 1);
        slots[b * CAP + pos] = make_uint2((unsigned)r, (unsigned)c);
    }
}

// exclusive scan of the 512 bucket counts -> global bucket starts + sentinel.
__global__ void scan512(const int* bcnt, int* bstart, int* rowst) {
    __shared__ int tmp[NB];
    int t = threadIdx.x;
    int v = bcnt[t];
    tmp[t] = v;
    __syncthreads();
    for (int off = 1; off < NB; off <<= 1) {
        int a = (t >= off) ? tmp[t - off] : 0;
        __syncthreads();
        tmp[t] += a;
        __syncthreads();
    }
    bstart[t] = tmp[t] - v;
    if (t == NB - 1) { bstart[NB] = N_EDGES; rowst[N_NODES] = N_EDGES; }
}

// ---------------------------------------------------------------------------
// One block per bucket: LDS hist/scan/scatter of the bucket's pairs, then
// coalesced global writes of cols + row_start at global offsets.
// ---------------------------------------------------------------------------
__global__ __launch_bounds__(256) void build_csr(const uint2* __restrict__ slots,
                                                 const int* __restrict__ bstart,
                                                 int* __restrict__ rowst,
                                                 int* __restrict__ cols) {
    __shared__ int hist[256];
    __shared__ int excl[256];
    __shared__ int cur[256];
    __shared__ int colbuf[CAP];
    int b = blockIdx.x;
    int node0 = b * NPB;
    int nn = N_NODES - node0;
    if (nn <= 0) return;
    if (nn > NPB) nn = NPB;
    int s = bstart[b];
    int cnt = bstart[b + 1] - s;
    const uint2* pairs = slots + (size_t)b * CAP;
    int t = threadIdx.x;
    hist[t] = 0;
    __syncthreads();
    for (int i = t; i < cnt; i += 256)
        atomicAdd(&hist[(int)pairs[i].x - node0], 1);
    __syncthreads();
    int v = hist[t];
    excl[t] = v;
    __syncthreads();
    for (int off = 1; off < 256; off <<= 1) {
        int a = (t >= off) ? excl[t - off] : 0;
        __syncthreads();
        excl[t] += a;
        __syncthreads();
    }
    int ex = excl[t] - v;
    if (t < nn) rowst[node0 + t] = s + ex;
    cur[t] = ex;
    __syncthreads();
    if (cnt <= CAP) {
        for (int i = t; i < cnt; i += 256) {
            uint2 pr = pairs[i];
            int pos = atomicAdd(&cur[(int)pr.x - node0], 1);
            colbuf[pos] = (int)pr.y;
        }
        __syncthreads();
        for (int i = t; i < cnt; i += 256) cols[s + i] = colbuf[i];
    } else {
        for (int i = t; i < cnt; i += 256) {
            uint2 pr = pairs[i];
            int pos = atomicAdd(&cur[(int)pr.x - node0], 1);
            cols[s + pos] = (int)pr.y;
        }
    }
}

// ---------------------------------------------------------------------------
// x (f32) -> xb (bf16), row-major.
// ---------------------------------------------------------------------------
__global__ void xconv(const float* __restrict__ x,
                      unsigned short* __restrict__ xb) {
    int i = blockIdx.x * 256 + threadIdx.x;
    float4 v = ((const float4*)x)[i];
    ushort4 o;
    o.x = f2bf(v.x); o.y = f2bf(v.y); o.z = f2bf(v.z); o.w = f2bf(v.w);
    ((ushort4*)xb)[i] = o;
}

// ---------------------------------------------------------------------------
// Aggregation + residual, all-bf16 gather: Hbf[n] = bf16(xb[n] + sum xb[c]).
// One wave per node; 16 independent row loads in flight per chunk.
// Near the random-64B-line fabric floor (~410MB line traffic).
// ---------------------------------------------------------------------------
__global__ __launch_bounds__(256) void agg_kernel(
    const unsigned short* __restrict__ xb,
    const int* __restrict__ row_start, const int* __restrict__ cols,
    unsigned short* __restrict__ Hbf) {
    int wave = threadIdx.x >> 6;
    int lane = threadIdx.x & 63;
    int node = blockIdx.x * 4 + wave;
    const unsigned* xbw = (const unsigned*)xb;     // 64 words per row
    unsigned selfw = xbw[(size_t)node * 64 + lane];
    float2 acc;
    acc.x = __uint_as_float(selfw << 16);
    acc.y = __uint_as_float(selfw & 0xffff0000u);
    int s = row_start[node], e = row_start[node + 1];
    s = __builtin_amdgcn_readfirstlane(s);
    e = __builtin_amdgcn_readfirstlane(e);
    int j = s;
    for (; j + 16 <= e; j += 16) {
        unsigned pw[16];
#pragma unroll
        for (int u = 0; u < 16; ++u) {
            int c = cols[j + u];                   // wave-uniform -> scalar
            pw[u] = xbw[(size_t)c * 64 + lane];
        }
#pragma unroll
        for (int u = 0; u < 16; ++u) {
            acc.x += __uint_as_float(pw[u] << 16);
            acc.y += __uint_as_float(pw[u] & 0xffff0000u);
        }
    }
    for (; j + 4 <= e; j += 4) {
        unsigned pw[4];
#pragma unroll
        for (int u = 0; u < 4; ++u) {
            int c = cols[j + u];
            pw[u] = xbw[(size_t)c * 64 + lane];
        }
#pragma unroll
        for (int u = 0; u < 4; ++u) {
            acc.x += __uint_as_float(pw[u] << 16);
            acc.y += __uint_as_float(pw[u] & 0xffff0000u);
        }
    }
    for (; j < e; ++j) {
        unsigned p = xbw[(size_t)cols[j] * 64 + lane];
        acc.x += __uint_as_float(p << 16);
        acc.y += __uint_as_float(p & 0xffff0000u);
    }
    unsigned pack = (unsigned)f2bf(acc.x) | ((unsigned)f2bf(acc.y) << 16);
    ((unsigned*)Hbf)[(size_t)node * 64 + lane] = pack;
}

// ---------------------------------------------------------------------------
// W (128x128 f32, [k][n]) -> bf16 transposed [n][k]. Tiny; L2-resident.
// ---------------------------------------------------------------------------
__global__ void convert_w(const float* __restrict__ W1,
                          const float* __restrict__ W2,
                          unsigned short* __restrict__ W1t,
                          unsigned short* __restrict__ W2t) {
    const float* W = blockIdx.x ? W2 : W1;
    unsigned short* Wt = blockIdx.x ? W2t : W1t;
    for (int i = threadIdx.x; i < DIM * DIM; i += 256) {
        int k = i >> 7, n = i & 127;
        Wt[n * DIM + k] = f2bf(W[i]);
    }
}

// ---------------------------------------------------------------------------
// Fused MLP: h2 = (relu(A@W1+b1))@W2 + b2 per 64-row tile. BN stats leave as
// per-block PARTIALS (no same-address global atomics -- the R5 64us kernel
// was a 1563-deep atomic serialization tail on 256 gstats addresses).
// ---------------------------------------------------------------------------
__global__ __launch_bounds__(256) void mlp_fused(
    const unsigned short* __restrict__ A,    // M_PAD x 128 bf16
    const unsigned short* __restrict__ B1t,  // W1^T bf16 [n][k]
    const unsigned short* __restrict__ B2t,  // W2^T bf16 [n][k]
    const float* __restrict__ bias1, const float* __restrict__ bias2,
    unsigned short* __restrict__ outb,       // M_PAD x 128 bf16
    float* __restrict__ gpart) {             // GBLK x 256 partials
    __shared__ unsigned short As[M_TILE * LPITCH];   // 17408 B
    __shared__ unsigned short Bs[DIM * LPITCH];      // 34816 B
    int t = threadIdx.x;
    int row0 = blockIdx.x * M_TILE;
    int lane = t & 63, wv = t >> 6;
    int m = lane & 15, g = lane >> 4;

#pragma unroll
    for (int i = 0; i < 4; ++i) {            // A: 64 rows x 16 chunks of 8 bf16
        int ch = t + 256 * i;
        int r = ch >> 4, cc = ch & 15;
        *(uint4*)(&As[r * LPITCH + cc * 8]) =
            *(const uint4*)(&A[(size_t)(row0 + r) * DIM + cc * 8]);
    }
#pragma unroll
    for (int i = 0; i < 8; ++i) {            // W1: 128 n-rows x 16 chunks
        int ch = t + 256 * i;
        int n = ch >> 4, cc = ch & 15;
        *(uint4*)(&Bs[n * LPITCH + cc * 8]) =
            *(const uint4*)(&B1t[n * DIM + cc * 8]);
    }
    __syncthreads();

    floatx4 acc1[8] = {};
#pragma unroll
    for (int kc = 0; kc < 4; ++kc) {
        short8 a = *(const short8*)(&As[(wv * 16 + m) * LPITCH + kc * 32 + g * 8]);
#pragma unroll
        for (int tt = 0; tt < 8; ++tt) {
            short8 b = *(const short8*)(&Bs[(tt * 16 + m) * LPITCH + kc * 32 + g * 8]);
            acc1[tt] = __builtin_amdgcn_mfma_f32_16x16x32_bf16(a, b, acc1[tt], 0, 0, 0);
        }
    }
    __syncthreads();                          // phase-1 LDS reads complete

    // issue W2 global loads early (latency hidden behind h1 LDS writes)
    uint4 wbuf[8];
#pragma unroll
    for (int i = 0; i < 8; ++i) {
        int ch = t + 256 * i;
        int n = ch >> 4, cc = ch & 15;
        wbuf[i] = *(const uint4*)(&B2t[n * DIM + cc * 8]);
    }
    // h1 = bf16(relu(acc1+b1)) scattered into As (C-layout -> A-layout)
#pragma unroll
    for (int tt = 0; tt < 8; ++tt) {
        int col = tt * 16 + m;
        float bv = bias1[col];
#pragma unroll
        for (int j = 0; j < 4; ++j) {
            int rl = wv * 16 + g * 4 + j;
            As[rl * LPITCH + col] = f2bf(fmaxf(acc1[tt][j] + bv, 0.f));
        }
    }
#pragma unroll
    for (int i = 0; i < 8; ++i) {
        int ch = t + 256 * i;
        int n = ch >> 4, cc = ch & 15;
        *(uint4*)(&Bs[n * LPITCH + cc * 8]) = wbuf[i];
    }
    __syncthreads();

    floatx4 acc2[8] = {};
#pragma unroll
    for (int kc = 0; kc < 4; ++kc) {
        short8 a = *(const short8*)(&As[(wv * 16 + m) * LPITCH + kc * 32 + g * 8]);
#pragma unroll
        for (int tt = 0; tt < 8; ++tt) {
            short8 b = *(const short8*)(&Bs[(tt * 16 + m) * LPITCH + kc * 32 + g * 8]);
            acc2[tt] = __builtin_amdgcn_mfma_f32_16x16x32_bf16(a, b, acc2[tt], 0, 0, 0);
        }
    }

    // epilogue: h2 store + per-block BN partial sums (LDS reduce, NO global
    // atomics -- one coalesced 1KB partial store instead)
    float* csum = (float*)As;
    float* csq = csum + DIM;
    __syncthreads();
    if (t < DIM) { csum[t] = 0.f; csq[t] = 0.f; }
    __syncthreads();
#pragma unroll
    for (int tt = 0; tt < 8; ++tt) {
        int col = tt * 16 + m;
        float bv = bias2[col];
        float s = 0.f, q = 0.f;
#pragma unroll
        for (int j = 0; j < 4; ++j) {
            int row = row0 + wv * 16 + g * 4 + j;
            float v = acc2[tt][j] + bv;
            outb[(size_t)row * DIM + col] = f2bf(v);
            if (row < N_NODES) { s += v; q += v * v; }
        }
        atomicAdd(&csum[col], s);
        atomicAdd(&csq[col], q);
    }
    __syncthreads();
    gpart[(size_t)blockIdx.x * 256 + t] = (t < DIM) ? csum[t] : csq[t - DIM];
}

// ---------------------------------------------------------------------------
// Reduce GBLK x 256 partials -> gstats[256]. 32 blocks, coalesced; 8K atomics
// total at 32-deep contention (vs 400K at 1563-deep before).
// ---------------------------------------------------------------------------
__global__ __launch_bounds__(256) void reduce_stats(
    const float* __restrict__ gpart, float* __restrict__ gstats) {
    int t = threadIdx.x;
    int chunk = (GBLK + 31) / 32;            // 49
    int r0 = blockIdx.x * chunk;
    int r1 = r0 + chunk < GBLK ? r0 + chunk : GBLK;
    float s = 0.f;
    for (int r = r0; r < r1; ++r) s += gpart[(size_t)r * 256 + t];
    atomicAdd(&gstats[t], s);
}

// ---------------------------------------------------------------------------
// BN finalize (redundant per block) + apply.
// ---------------------------------------------------------------------------
__global__ __launch_bounds__(256) void bn_apply(
    const unsigned short* __restrict__ H2, const float* __restrict__ gstats,
    const float* __restrict__ gamma, const float* __restrict__ beta,
    float* __restrict__ out) {
    __shared__ float sc_s[DIM], sh_s[DIM];
    int t = threadIdx.x;
    if (t < DIM) {
        float mean = gstats[t] * (1.0f / N_NODES);
        float m2 = gstats[DIM + t] * (1.0f / N_NODES);
        float var = m2 - mean * mean;
        float inv = rsqrtf(var + EPS_BN);
        float sc = gamma[t] * inv;
        sc_s[t] = sc;
        sh_s[t] = beta[t] - mean * sc;
    }
    __syncthreads();
    int i = blockIdx.x * 256 + t;
    int j4 = (i & 31) * 4;
    ushort4 hv = ((const ushort4*)H2)[i];
    float4 o;
    o.x = bf2f(hv.x) * sc_s[j4 + 0] + sh_s[j4 + 0];
    o.y = bf2f(hv.y) * sc_s[j4 + 1] + sh_s[j4 + 1];
    o.z = bf2f(hv.z) * sc_s[j4 + 2] + sh_s[j4 + 2];
    o.w = bf2f(hv.w) * sc_s[j4 + 3] + sh_s[j4 + 3];
    ((float4*)out)[i] = o;
}

// ---------------------------------------------------------------------------
extern "C" void kernel_launch(void* const* d_in, const int* in_sizes, int n_in,
                              void* d_out, int out_size, void* d_ws,
                              size_t ws_size, hipStream_t stream) {
    (void)in_sizes; (void)n_in; (void)out_size; (void)ws_size;
    const float* x     = (const float*)d_in[0];
    const void*  eidx  = d_in[1];
    const float* W1    = (const float*)d_in[2];
    const float* b1    = (const float*)d_in[3];
    const float* W2    = (const float*)d_in[4];
    const float* b2    = (const float*)d_in[5];
    const float* gamma = (const float*)d_in[6];
    const float* beta  = (const float*)d_in[7];
    float* out = (float*)d_out;

    char* p = (char*)d_ws;
    auto alloc = [&](size_t bytes) {
        char* r = p;
        p += (bytes + 255) & ~(size_t)255;
        return r;
    };
    unsigned short* Hbf  = (unsigned short*)alloc((size_t)M_PAD * DIM * 2); // 25.6MB
    unsigned short* h2bf = (unsigned short*)alloc((size_t)M_PAD * DIM * 2); // 25.6MB
    // slots (16.8MB) alias h2bf: slots dead after build_csr; h2 written later
    uint2* slots = (uint2*)h2bf;
    unsigned short* xb = (unsigned short*)alloc((size_t)N_NODES * DIM * 2);  // 25.6MB
    int*   cols   = (int*)alloc((size_t)N_EDGES * 4);                        // 6.4MB
    float* gpart  = (float*)alloc((size_t)GBLK * 256 * 4);                   // 1.6MB
    int*   rowst  = (int*)alloc((size_t)(N_NODES + 1) * 4);
    int*   bcur   = (int*)alloc(NB * 4);
    int*   bstart = (int*)alloc((NB + 1) * 4);
    unsigned short* W1t = (unsigned short*)alloc(DIM * DIM * 2);
    unsigned short* W2t = (unsigned short*)alloc(DIM * DIM * 2);
    float* gstats = (float*)alloc(2 * DIM * 4);

    hipMemsetAsync(bcur, 0, NB * 4, stream);
    hipMemsetAsync(gstats, 0, 2 * DIM * 4, stream);

    convert_w<<<2, 256, 0, stream>>>(W1, W2, W1t, W2t);
    bin_scatter<<<NB, 256, 0, stream>>>(eidx, bcur, slots);
    scan512<<<1, NB, 0, stream>>>(bcur, bstart, rowst);
    build_csr<<<NB, 256, 0, stream>>>(slots, bstart, rowst, cols);

    xconv<<<N_NODES * DIM / 4 / 256, 256, 0, stream>>>(x, xb);
    agg_kernel<<<N_NODES / 4, 256, 0, stream>>>(xb, rowst, cols, Hbf);

    mlp_fused<<<GBLK, 256, 0, stream>>>(Hbf, W1t, W2t, b1, b2, h2bf, gpart);
    reduce_stats<<<32, 256, 0, stream>>>(gpart, gstats);
    bn_apply<<<(N_NODES * DIM / 4) / 256, 256, 0, stream>>>(h2bf, gstats,
                                                            gamma, beta, out);
}

// Round 7
// 310.755 us; speedup vs baseline: 2.0740x; 1.0477x over previous
//
#include <hip/hip_runtime.h>

#define N_NODES 100000
#define N_EDGES 1600000
#define DIM     128
#define EPS_BN  1e-5f
#define NB      512      // buckets
#define NPB     196      // nodes per bucket (512*196 >= 100000)
#define NBLK    256      // bin_scatter blocks
#define EPB     6250     // edges per bin_scatter block (256*6250 == N_EDGES)
#define CAP     4096     // slot capacity per bucket (mean 3125, sigma~56)
#define M_TILE  64
#define M_PAD   100032   // 1563 * 64
#define GBLK    1563     // M_PAD / M_TILE
#define LPITCH  136      // LDS pitch in bf16 units (272B = 17*16B, b128-aligned)

typedef __attribute__((ext_vector_type(8))) short short8;
typedef __attribute__((ext_vector_type(4))) float floatx4;

__device__ __forceinline__ unsigned short f2bf(float f) {   // RNE bf16 bits
    unsigned u = __float_as_uint(f);
    return (unsigned short)((u + 0x7FFF + ((u >> 16) & 1)) >> 16);
}
__device__ __forceinline__ float bf2f(unsigned short b) {
    return __uint_as_float((unsigned)b << 16);
}

// int64 layout => odd int32 words all zero. Wave-uniform result.
__device__ __forceinline__ int detect64(const void* eidx) {
    int v = ((const int*)eidx)[2 * (threadIdx.x & 63) + 1];
    unsigned long long b = __ballot(v != 0);
    return (b == 0ULL) ? 1 : 0;
}
__device__ __forceinline__ int load_row(const void* eidx, int is64, int e) {
    if (is64) return (int)((const long long*)eidx)[e];
    return ((const int*)eidx)[e];
}
__device__ __forceinline__ int load_col(const void* eidx, int is64, int e) {
    if (is64) return (int)((const long long*)eidx)[N_EDGES + e];
    return ((const int*)eidx)[N_EDGES + e];
}

// ---------------------------------------------------------------------------
// convert_w + workspace init (replaces 2 memsets): blocks 0/1 transpose W1/W2
// to bf16 [n][k]; block 2 zeroes bcur + gstats.
// ---------------------------------------------------------------------------
__global__ void convert_w(const float* __restrict__ W1,
                          const float* __restrict__ W2,
                          unsigned short* __restrict__ W1t,
                          unsigned short* __restrict__ W2t,
                          int* __restrict__ bcur, float* __restrict__ gstats) {
    if (blockIdx.x == 2) {
        int t = threadIdx.x;
        if (t < NB) bcur[t] = 0;
        if (t < 256) { if (t < NB - 256) bcur[256 + t] = 0; }
        bcur[256 + threadIdx.x] = 0;          // covers 256..511
        if (t < 2 * DIM) gstats[t] = 0.f;
        return;
    }
    const float* W = blockIdx.x ? W2 : W1;
    unsigned short* Wt = blockIdx.x ? W2t : W1t;
    for (int i = threadIdx.x; i < DIM * DIM; i += 256) {
        int k = i >> 7, n = i & 127;
        Wt[n * DIM + k] = f2bf(W[i]);
    }
}

// ---------------------------------------------------------------------------
// bin_scatter v2: hist -> LDS scan -> per-bucket global range claim -> LDS
// bucket-sorted staging (packed 4B: row_local<<24 | col) with precomputed
// absolute slot addresses -> LINEAR copy out (coalescer forms full lines).
// LDS: 3*2KB tables + 25KB stage + 25KB gaddr = 56KB.
// ---------------------------------------------------------------------------
__global__ __launch_bounds__(256) void bin_scatter(const void* eidx, int* bcur,
                                                   unsigned* __restrict__ slots) {
    __shared__ int lh[NB];
    __shared__ int lbase[NB];
    __shared__ int loff[NB];
    __shared__ unsigned stage[EPB];
    __shared__ int gaddr[EPB];
    int t = threadIdx.x;
    int is64 = detect64(eidx);
    lh[t] = 0; lh[t + 256] = 0;
    __syncthreads();
    int base = blockIdx.x * EPB;
    for (int i = t; i < EPB; i += 256) {
        int r = load_row(eidx, is64, base + i);
        atomicAdd(&lh[r / NPB], 1);
    }
    __syncthreads();
    // inclusive scan of lh[0..511] into loff (256 threads, 2 elems each)
    loff[t] = lh[t]; loff[t + 256] = lh[t + 256];
    __syncthreads();
    for (int off = 1; off < NB; off <<= 1) {
        int a0 = (t >= off) ? loff[t - off] : 0;
        int a1 = (t + 256 >= off) ? loff[t + 256 - off] : 0;
        __syncthreads();
        loff[t] += a0; loff[t + 256] += a1;
        __syncthreads();
    }
    // claim global ranges, make loff exclusive, reset lh for scatter cursors
#pragma unroll
    for (int q = 0; q < 2; ++q) {
        int i = t + 256 * q;
        int c = lh[i];
        lbase[i] = c ? atomicAdd(&bcur[i], c) : 0;
        loff[i] -= c;
        lh[i] = 0;
    }
    __syncthreads();
    for (int i = t; i < EPB; i += 256) {
        int r = load_row(eidx, is64, base + i);
        int c = load_col(eidx, is64, base + i);
        int b = r / NPB;
        int pos = atomicAdd(&lh[b], 1);
        int idx = loff[b] + pos;
        stage[idx] = ((unsigned)(r - b * NPB) << 24) | (unsigned)c;
        gaddr[idx] = b * CAP + lbase[b] + pos;
    }
    __syncthreads();
    for (int i = t; i < EPB; i += 256)        // linear: runs coalesce to lines
        slots[gaddr[i]] = stage[i];
}

// ---------------------------------------------------------------------------
// build_csr: in-block redundant scan of bucket counts (drops scan512 kernel),
// then LDS hist/scan/scatter of this bucket's packed pairs, coalesced out.
// ---------------------------------------------------------------------------
__global__ __launch_bounds__(256) void build_csr(const unsigned* __restrict__ slots,
                                                 const int* __restrict__ bcnt,
                                                 int* __restrict__ rowst,
                                                 int* __restrict__ cols) {
    __shared__ int tmp[NB];
    __shared__ int hist[256];
    __shared__ int excl[256];
    __shared__ int cur[256];
    __shared__ int colbuf[CAP];
    int t = threadIdx.x;
    int b = blockIdx.x;
    // inclusive scan of bcnt into tmp
    tmp[t] = bcnt[t]; tmp[t + 256] = bcnt[t + 256];
    __syncthreads();
    for (int off = 1; off < NB; off <<= 1) {
        int a0 = (t >= off) ? tmp[t - off] : 0;
        int a1 = (t + 256 >= off) ? tmp[t + 256 - off] : 0;
        __syncthreads();
        tmp[t] += a0; tmp[t + 256] += a1;
        __syncthreads();
    }
    int cnt = bcnt[b];
    int s = tmp[b] - cnt;                     // exclusive start
    int node0 = b * NPB;
    int nn = N_NODES - node0;
    if (nn > NPB) nn = NPB;
    const unsigned* pairs = slots + (size_t)b * CAP;
    hist[t] = 0;
    if (b == NB - 1 && t == 0) rowst[N_NODES] = N_EDGES;
    __syncthreads();
    for (int i = t; i < cnt; i += 256)
        atomicAdd(&hist[(int)(pairs[i] >> 24)], 1);
    __syncthreads();
    int v = hist[t];
    excl[t] = v;
    __syncthreads();
    for (int off = 1; off < 256; off <<= 1) {
        int a = (t >= off) ? excl[t - off] : 0;
        __syncthreads();
        excl[t] += a;
        __syncthreads();
    }
    int ex = excl[t] - v;
    if (t < nn) rowst[node0 + t] = s + ex;
    cur[t] = ex;
    __syncthreads();
    for (int i = t; i < cnt; i += 256) {
        unsigned pr = pairs[i];
        int pos = atomicAdd(&cur[pr >> 24], 1);
        colbuf[pos] = (int)(pr & 0xFFFFFFu);
    }
    __syncthreads();
    for (int i = t; i < cnt; i += 256) cols[s + i] = colbuf[i];
}

// ---------------------------------------------------------------------------
// x (f32) -> xb (bf16), row-major.
// ---------------------------------------------------------------------------
__global__ void xconv(const float* __restrict__ x,
                      unsigned short* __restrict__ xb) {
    int i = blockIdx.x * 256 + threadIdx.x;
    float4 v = ((const float4*)x)[i];
    ushort4 o;
    o.x = f2bf(v.x); o.y = f2bf(v.y); o.z = f2bf(v.z); o.w = f2bf(v.w);
    ((ushort4*)xb)[i] = o;
}

// ---------------------------------------------------------------------------
// Aggregation + residual: Hbf[n] = bf16(xb[n] + sum xb[c]).
// One wave per node. Degree is Poisson(16): fully-predicated 16- or 32-load
// groups put the WHOLE neighbor list in flight in one round trip (padding
// loads use a clamped duplicate index -> L1 hit, no fabric cost; masked
// accumulate). d>32 (P~2e-4) falls back to a 16-chunk loop.
// ---------------------------------------------------------------------------
__global__ __launch_bounds__(256) void agg_kernel(
    const unsigned short* __restrict__ xb,
    const int* __restrict__ row_start, const int* __restrict__ cols,
    unsigned short* __restrict__ Hbf) {
    int wave = threadIdx.x >> 6;
    int lane = threadIdx.x & 63;
    int node = blockIdx.x * 4 + wave;
    const unsigned* xbw = (const unsigned*)xb;     // 64 words per row
    unsigned selfw = xbw[(size_t)node * 64 + lane];
    float2 acc;
    acc.x = __uint_as_float(selfw << 16);
    acc.y = __uint_as_float(selfw & 0xffff0000u);
    int s = row_start[node], e = row_start[node + 1];
    s = __builtin_amdgcn_readfirstlane(s);
    e = __builtin_amdgcn_readfirstlane(e);
    int d = e - s;
    if (d <= 16) {
        unsigned pw[16];
#pragma unroll
        for (int u = 0; u < 16; ++u) {
            int idx = s + u;
            int ci = (idx < e) ? idx : s;              // clamp: dup row, L1 hit
            pw[u] = xbw[(size_t)cols[ci] * 64 + lane];
        }
#pragma unroll
        for (int u = 0; u < 16; ++u) {
            unsigned w = (u < d) ? pw[u] : 0u;         // masked accumulate
            acc.x += __uint_as_float(w << 16);
            acc.y += __uint_as_float(w & 0xffff0000u);
        }
    } else if (d <= 32) {
        unsigned pw[32];
#pragma unroll
        for (int u = 0; u < 32; ++u) {
            int idx = s + u;
            int ci = (idx < e) ? idx : s;
            pw[u] = xbw[(size_t)cols[ci] * 64 + lane];
        }
#pragma unroll
        for (int u = 0; u < 32; ++u) {
            unsigned w = (u < d) ? pw[u] : 0u;
            acc.x += __uint_as_float(w << 16);
            acc.y += __uint_as_float(w & 0xffff0000u);
        }
    } else {
        int j = s;
        for (; j + 16 <= e; j += 16) {
            unsigned pw[16];
#pragma unroll
            for (int u = 0; u < 16; ++u)
                pw[u] = xbw[(size_t)cols[j + u] * 64 + lane];
#pragma unroll
            for (int u = 0; u < 16; ++u) {
                acc.x += __uint_as_float(pw[u] << 16);
                acc.y += __uint_as_float(pw[u] & 0xffff0000u);
            }
        }
        for (; j < e; ++j) {
            unsigned pv = xbw[(size_t)cols[j] * 64 + lane];
            acc.x += __uint_as_float(pv << 16);
            acc.y += __uint_as_float(pv & 0xffff0000u);
        }
    }
    unsigned pack = (unsigned)f2bf(acc.x) | ((unsigned)f2bf(acc.y) << 16);
    ((unsigned*)Hbf)[(size_t)node * 64 + lane] = pack;
}

// ---------------------------------------------------------------------------
// Fused MLP: h2 = (relu(A@W1+b1))@W2 + b2 per 64-row tile; BN stats leave as
// per-block partials (no same-address global atomics).
// ---------------------------------------------------------------------------
__global__ __launch_bounds__(256) void mlp_fused(
    const unsigned short* __restrict__ A,    // M_PAD x 128 bf16
    const unsigned short* __restrict__ B1t,  // W1^T bf16 [n][k]
    const unsigned short* __restrict__ B2t,  // W2^T bf16 [n][k]
    const float* __restrict__ bias1, const float* __restrict__ bias2,
    unsigned short* __restrict__ outb,       // M_PAD x 128 bf16
    float* __restrict__ gpart) {             // GBLK x 256 partials
    __shared__ unsigned short As[M_TILE * LPITCH];   // 17408 B
    __shared__ unsigned short Bs[DIM * LPITCH];      // 34816 B
    int t = threadIdx.x;
    int row0 = blockIdx.x * M_TILE;
    int lane = t & 63, wv = t >> 6;
    int m = lane & 15, g = lane >> 4;

#pragma unroll
    for (int i = 0; i < 4; ++i) {
        int ch = t + 256 * i;
        int r = ch >> 4, cc = ch & 15;
        *(uint4*)(&As[r * LPITCH + cc * 8]) =
            *(const uint4*)(&A[(size_t)(row0 + r) * DIM + cc * 8]);
    }
#pragma unroll
    for (int i = 0; i < 8; ++i) {
        int ch = t + 256 * i;
        int n = ch >> 4, cc = ch & 15;
        *(uint4*)(&Bs[n * LPITCH + cc * 8]) =
            *(const uint4*)(&B1t[n * DIM + cc * 8]);
    }
    __syncthreads();

    floatx4 acc1[8] = {};
#pragma unroll
    for (int kc = 0; kc < 4; ++kc) {
        short8 a = *(const short8*)(&As[(wv * 16 + m) * LPITCH + kc * 32 + g * 8]);
#pragma unroll
        for (int tt = 0; tt < 8; ++tt) {
            short8 b = *(const short8*)(&Bs[(tt * 16 + m) * LPITCH + kc * 32 + g * 8]);
            acc1[tt] = __builtin_amdgcn_mfma_f32_16x16x32_bf16(a, b, acc1[tt], 0, 0, 0);
        }
    }
    __syncthreads();

    uint4 wbuf[8];
#pragma unroll
    for (int i = 0; i < 8; ++i) {
        int ch = t + 256 * i;
        int n = ch >> 4, cc = ch & 15;
        wbuf[i] = *(const uint4*)(&B2t[n * DIM + cc * 8]);
    }
#pragma unroll
    for (int tt = 0; tt < 8; ++tt) {
        int col = tt * 16 + m;
        float bv = bias1[col];
#pragma unroll
        for (int j = 0; j < 4; ++j) {
            int rl = wv * 16 + g * 4 + j;
            As[rl * LPITCH + col] = f2bf(fmaxf(acc1[tt][j] + bv, 0.f));
        }
    }
#pragma unroll
    for (int i = 0; i < 8; ++i) {
        int ch = t + 256 * i;
        int n = ch >> 4, cc = ch & 15;
        *(uint4*)(&Bs[n * LPITCH + cc * 8]) = wbuf[i];
    }
    __syncthreads();

    floatx4 acc2[8] = {};
#pragma unroll
    for (int kc = 0; kc < 4; ++kc) {
        short8 a = *(const short8*)(&As[(wv * 16 + m) * LPITCH + kc * 32 + g * 8]);
#pragma unroll
        for (int tt = 0; tt < 8; ++tt) {
            short8 b = *(const short8*)(&Bs[(tt * 16 + m) * LPITCH + kc * 32 + g * 8]);
            acc2[tt] = __builtin_amdgcn_mfma_f32_16x16x32_bf16(a, b, acc2[tt], 0, 0, 0);
        }
    }

    float* csum = (float*)As;
    float* csq = csum + DIM;
    __syncthreads();
    if (t < DIM) { csum[t] = 0.f; csq[t] = 0.f; }
    __syncthreads();
#pragma unroll
    for (int tt = 0; tt < 8; ++tt) {
        int col = tt * 16 + m;
        float bv = bias2[col];
        float s = 0.f, q = 0.f;
#pragma unroll
        for (int j = 0; j < 4; ++j) {
            int row = row0 + wv * 16 + g * 4 + j;
            float v = acc2[tt][j] + bv;
            outb[(size_t)row * DIM + col] = f2bf(v);
            if (row < N_NODES) { s += v; q += v * v; }
        }
        atomicAdd(&csum[col], s);
        atomicAdd(&csq[col], q);
    }
    __syncthreads();
    gpart[(size_t)blockIdx.x * 256 + t] = (t < DIM) ? csum[t] : csq[t - DIM];
}

// ---------------------------------------------------------------------------
// Reduce GBLK x 256 partials -> gstats[256].
// ---------------------------------------------------------------------------
__global__ __launch_bounds__(256) void reduce_stats(
    const float* __restrict__ gpart, float* __restrict__ gstats) {
    int t = threadIdx.x;
    int chunk = (GBLK + 31) / 32;            // 49
    int r0 = blockIdx.x * chunk;
    int r1 = r0 + chunk < GBLK ? r0 + chunk : GBLK;
    float s = 0.f;
    for (int r = r0; r < r1; ++r) s += gpart[(size_t)r * 256 + t];
    atomicAdd(&gstats[t], s);
}

// ---------------------------------------------------------------------------
// BN finalize (redundant per block) + apply.
// ---------------------------------------------------------------------------
__global__ __launch_bounds__(256) void bn_apply(
    const unsigned short* __restrict__ H2, const float* __restrict__ gstats,
    const float* __restrict__ gamma, const float* __restrict__ beta,
    float* __restrict__ out) {
    __shared__ float sc_s[DIM], sh_s[DIM];
    int t = threadIdx.x;
    if (t < DIM) {
        float mean = gstats[t] * (1.0f / N_NODES);
        float m2 = gstats[DIM + t] * (1.0f / N_NODES);
        float var = m2 - mean * mean;
        float inv = rsqrtf(var + EPS_BN);
        float sc = gamma[t] * inv;
        sc_s[t] = sc;
        sh_s[t] = beta[t] - mean * sc;
    }
    __syncthreads();
    int i = blockIdx.x * 256 + t;
    int j4 = (i & 31) * 4;
    ushort4 hv = ((const ushort4*)H2)[i];
    float4 o;
    o.x = bf2f(hv.x) * sc_s[j4 + 0] + sh_s[j4 + 0];
    o.y = bf2f(hv.y) * sc_s[j4 + 1] + sh_s[j4 + 1];
    o.z = bf2f(hv.z) * sc_s[j4 + 2] + sh_s[j4 + 2];
    o.w = bf2f(hv.w) * sc_s[j4 + 3] + sh_s[j4 + 3];
    ((float4*)out)[i] = o;
}

// ---------------------------------------------------------------------------
extern "C" void kernel_launch(void* const* d_in, const int* in_sizes, int n_in,
                              void* d_out, int out_size, void* d_ws,
                              size_t ws_size, hipStream_t stream) {
    (void)in_sizes; (void)n_in; (void)out_size; (void)ws_size;
    const float* x     = (const float*)d_in[0];
    const void*  eidx  = d_in[1];
    const float* W1    = (const float*)d_in[2];
    const float* b1    = (const float*)d_in[3];
    const float* W2    = (const float*)d_in[4];
    const float* b2    = (const float*)d_in[5];
    const float* gamma = (const float*)d_in[6];
    const float* beta  = (const float*)d_in[7];
    float* out = (float*)d_out;

    char* p = (char*)d_ws;
    auto alloc = [&](size_t bytes) {
        char* r = p;
        p += (bytes + 255) & ~(size_t)255;
        return r;
    };
    unsigned short* Hbf  = (unsigned short*)alloc((size_t)M_PAD * DIM * 2); // 25.6MB
    unsigned short* h2bf = (unsigned short*)alloc((size_t)M_PAD * DIM * 2); // 25.6MB
    // slots (8.4MB, packed 4B) alias h2bf: dead before mlp writes h2
    unsigned* slots = (unsigned*)h2bf;
    unsigned short* xb = (unsigned short*)alloc((size_t)N_NODES * DIM * 2);  // 25.6MB
    int*   cols   = (int*)alloc((size_t)(N_EDGES + 64) * 4);                 // 6.4MB
    float* gpart  = (float*)alloc((size_t)GBLK * 256 * 4);                   // 1.6MB
    int*   rowst  = (int*)alloc((size_t)(N_NODES + 1) * 4);
    int*   bcur   = (int*)alloc(NB * 4);
    unsigned short* W1t = (unsigned short*)alloc(DIM * DIM * 2);
    unsigned short* W2t = (unsigned short*)alloc(DIM * DIM * 2);
    float* gstats = (float*)alloc(2 * DIM * 4);

    convert_w<<<3, 256, 0, stream>>>(W1, W2, W1t, W2t, bcur, gstats);
    bin_scatter<<<NBLK, 256, 0, stream>>>(eidx, bcur, slots);
    build_csr<<<NB, 256, 0, stream>>>(slots, bcur, rowst, cols);

    xconv<<<N_NODES * DIM / 4 / 256, 256, 0, stream>>>(x, xb);
    agg_kernel<<<N_NODES / 4, 256, 0, stream>>>(xb, rowst, cols, Hbf);

    mlp_fused<<<GBLK, 256, 0, stream>>>(Hbf, W1t, W2t, b1, b2, h2bf, gpart);
    reduce_stats<<<32, 256, 0, stream>>>(gpart, gstats);
    bn_apply<<<(N_NODES * DIM / 4) / 256, 256, 0, stream>>>(h2bf, gstats,
                                                            gamma, beta, out);
}